// Round 1
// baseline (1055.477 us; speedup 1.0000x reference)
//
#include <hip/hip_runtime.h>
#include <hip/hip_bf16.h>

// Problem constants
#define N_    8192
#define K_    200
#define CIN_  512
#define HID_  256
#define COUT_ 40
#define E_    5
#define MH_   64
#define KG_   40
#define EPS_  1e-5f

// Workspace layout (floats):
//  [0,256)        Vsum (K_=200 used, padded)
//  [256,768)      bnsum: sum[256], sumsq[256]
//  [768,103168)   T = U^T X   [200][512]
//  [103168,103424) s[200]
//  [103424,154624) G = T@Ww   [200][256]
#define WS_VSUM  0
#define WS_BNSUM 256
#define WS_T     768
#define WS_S     103168
#define WS_G     103424

// ---------------------------------------------------------------------------
// Expert MLP: v[n,e,kg] = W3 . relu(W2^T relu(u*W1+b1) + b2) + b3, summed over n
// grid: (E_, N_/32); block 256. Each block: expert e, 32 rows x 40 kg = 1280 elems.
// ---------------------------------------------------------------------------
__global__ __launch_bounds__(256) void k_expert(
    const float* __restrict__ U,
    const float* __restrict__ eW1, const float* __restrict__ eb1,
    const float* __restrict__ eW2, const float* __restrict__ eb2,
    const float* __restrict__ eW3, const float* __restrict__ eb3,
    float* __restrict__ Vsum)
{
    const int e   = blockIdx.x;
    const int r0  = blockIdx.y * 32;
    const int tid = threadIdx.x;

    __shared__ float sW1[MH_], sb1[MH_], sb2[MH_], sW3[MH_];
    __shared__ float sW2[MH_][MH_];
    __shared__ float colsum[KG_];

    if (tid < MH_) {
        sW1[tid] = eW1[e*MH_ + tid];
        sb1[tid] = eb1[e*MH_ + tid];
        sb2[tid] = eb2[e*MH_ + tid];
        sW3[tid] = eW3[e*MH_ + tid];
    }
    for (int j = tid; j < MH_*MH_; j += 256)
        sW2[j >> 6][j & 63] = eW2[e*MH_*MH_ + j];
    if (tid < KG_) colsum[tid] = 0.f;
    const float b3 = eb3[e];
    __syncthreads();

    for (int i = 0; i < 5; ++i) {
        const int idx = tid + i*256;            // [0,1280)
        const int n   = r0 + idx / KG_;
        const int kg  = idx % KG_;
        const float u = U[n*K_ + e*KG_ + kg];

        float h1[MH_];
        #pragma unroll
        for (int h = 0; h < MH_; ++h)
            h1[h] = fmaxf(u * sW1[h] + sb1[h], 0.f);

        float v = b3;
        for (int g0 = 0; g0 < MH_; g0 += 4) {
            float a0 = sb2[g0+0], a1 = sb2[g0+1], a2 = sb2[g0+2], a3 = sb2[g0+3];
            #pragma unroll
            for (int h = 0; h < MH_; ++h) {
                const float4 w = *reinterpret_cast<const float4*>(&sW2[h][g0]);
                a0 += h1[h]*w.x; a1 += h1[h]*w.y;
                a2 += h1[h]*w.z; a3 += h1[h]*w.w;
            }
            v += fmaxf(a0,0.f)*sW3[g0+0] + fmaxf(a1,0.f)*sW3[g0+1]
               + fmaxf(a2,0.f)*sW3[g0+2] + fmaxf(a3,0.f)*sW3[g0+3];
        }
        atomicAdd(&colsum[kg], v);
    }
    __syncthreads();
    if (tid < KG_) atomicAdd(&Vsum[e*KG_ + tid], colsum[tid]);
}

// ---------------------------------------------------------------------------
// Gate: stats = mean La per group; g = softmax(relu(stats@gW1+gb1)@gW2+gb2)
// s[k] = g[k/40] * Vsum[k] / N
// ---------------------------------------------------------------------------
__global__ void k_gate(
    const float* __restrict__ La,
    const float* __restrict__ gW1, const float* __restrict__ gb1,
    const float* __restrict__ gW2, const float* __restrict__ gb2,
    const float* __restrict__ Vsum, float* __restrict__ s)
{
    __shared__ float sg[E_];
    const int tid = threadIdx.x;
    if (tid == 0) {
        float stats[E_], g1[E_], g2[E_];
        for (int e = 0; e < E_; ++e) {
            float acc = 0.f;
            for (int k = 0; k < KG_; ++k) acc += La[e*KG_ + k];
            stats[e] = acc * (1.0f/KG_);
        }
        for (int j = 0; j < E_; ++j) {
            float acc = gb1[j];
            for (int i = 0; i < E_; ++i) acc += stats[i]*gW1[i*E_ + j];
            g1[j] = fmaxf(acc, 0.f);
        }
        float m = -1e30f;
        for (int j = 0; j < E_; ++j) {
            float acc = gb2[j];
            for (int i = 0; i < E_; ++i) acc += g1[i]*gW2[i*E_ + j];
            g2[j] = acc;
            m = fmaxf(m, acc);
        }
        float ssum = 0.f;
        for (int j = 0; j < E_; ++j) { g2[j] = expf(g2[j]-m); ssum += g2[j]; }
        for (int j = 0; j < E_; ++j) sg[j] = g2[j] / ssum;
    }
    __syncthreads();
    if (tid < K_) s[tid] = sg[tid / KG_] * Vsum[tid] * (1.0f/N_);
}

// ---------------------------------------------------------------------------
// T = U^T @ X   [200][512]
// grid: (16 ctiles of 32, 16 nsplits of 512); block 256.
// Thread (kq = tid>>5 in 0..7, cl = tid&31): acc over 25 k-values kq+8i.
// ---------------------------------------------------------------------------
__global__ __launch_bounds__(256) void k_ut_x(
    const float* __restrict__ U, const float* __restrict__ X,
    float* __restrict__ T)
{
    const int c0  = blockIdx.x * 32;
    const int n0  = blockIdx.y * 512;
    const int tid = threadIdx.x;
    const int cl  = tid & 31;
    const int kq  = tid >> 5;

    __shared__ float sU[8][K_];
    __shared__ float sX[8][32];

    float acc[25];
    #pragma unroll
    for (int i = 0; i < 25; ++i) acc[i] = 0.f;

    for (int nb = 0; nb < 512; nb += 8) {
        __syncthreads();
        for (int j = tid; j < 8*K_; j += 256) {
            const int r = j / K_, k = j % K_;
            sU[r][k] = U[(n0+nb+r)*K_ + k];
        }
        sX[kq][cl] = X[(n0+nb+kq)*CIN_ + c0 + cl];
        __syncthreads();
        #pragma unroll
        for (int r = 0; r < 8; ++r) {
            const float xv = sX[r][cl];
            #pragma unroll
            for (int i = 0; i < 25; ++i)
                acc[i] += sU[r][kq + 8*i] * xv;
        }
    }
    #pragma unroll
    for (int i = 0; i < 25; ++i)
        atomicAdd(&T[(kq + 8*i)*CIN_ + c0 + cl], acc[i]);
}

// ---------------------------------------------------------------------------
// G = T @ Ww   [200][256]
// grid: 25 blocks of 8 k-rows; thread = output column.
// ---------------------------------------------------------------------------
__global__ __launch_bounds__(256) void k_g(
    const float* __restrict__ T, const float* __restrict__ Ww,
    float* __restrict__ G)
{
    const int k0 = blockIdx.x * 8;
    const int c  = threadIdx.x;
    float acc[8];
    #pragma unroll
    for (int r = 0; r < 8; ++r) acc[r] = 0.f;
    for (int ci = 0; ci < CIN_; ++ci) {
        const float w = Ww[ci*HID_ + c];
        #pragma unroll
        for (int r = 0; r < 8; ++r)
            acc[r] += T[(k0+r)*CIN_ + ci] * w;
    }
    #pragma unroll
    for (int r = 0; r < 8; ++r)
        G[(k0+r)*HID_ + c] = acc[r];
}

// ---------------------------------------------------------------------------
// hidden = (U*s) @ G + Wb   [8192][256], written straight into d_out region 1
// grid: (2 ctiles of 128, 128 ntiles of 64); block 256; 32 acc/thread.
// ---------------------------------------------------------------------------
__global__ __launch_bounds__(256) void k_hidden(
    const float* __restrict__ U, const float* __restrict__ s,
    const float* __restrict__ G, const float* __restrict__ Wb,
    float* __restrict__ hid)
{
    const int c0  = blockIdx.x * 128;
    const int n0  = blockIdx.y * 64;
    const int tid = threadIdx.x;
    const int cl  = tid & 127;
    const int nr  = tid >> 7;          // 0..1

    __shared__ float ss[K_];
    __shared__ float sUs[64][KG_];
    __shared__ float sG[KG_][128];

    if (tid < K_) ss[tid] = s[tid];
    float acc[32];
    #pragma unroll
    for (int i = 0; i < 32; ++i) acc[i] = 0.f;
    __syncthreads();

    for (int k0 = 0; k0 < K_; k0 += KG_) {
        __syncthreads();
        for (int j = tid; j < 64*KG_; j += 256) {
            const int r = j / KG_, kk = j % KG_;
            sUs[r][kk] = U[(n0+r)*K_ + k0 + kk] * ss[k0+kk];
        }
        for (int j = tid; j < KG_*128; j += 256) {
            const int r = j >> 7, cc = j & 127;
            sG[r][cc] = G[(k0+r)*HID_ + c0 + cc];
        }
        __syncthreads();
        #pragma unroll 8
        for (int kk = 0; kk < KG_; ++kk) {
            const float gv = sG[kk][cl];
            #pragma unroll
            for (int i = 0; i < 32; ++i)
                acc[i] += sUs[nr + 2*i][kk] * gv;
        }
    }
    const float wb = Wb[c0 + cl];
    #pragma unroll
    for (int i = 0; i < 32; ++i)
        hid[(n0 + nr + 2*i)*HID_ + c0 + cl] = acc[i] + wb;
}

// ---------------------------------------------------------------------------
// BN batch stats: per-column sum & sumsq over n
// ---------------------------------------------------------------------------
__global__ __launch_bounds__(256) void k_bnstat(
    const float* __restrict__ hid, float* __restrict__ bnsum)
{
    const int c  = threadIdx.x;
    const int n0 = blockIdx.x * 128;
    float sm = 0.f, sq = 0.f;
    for (int r = 0; r < 128; ++r) {
        const float v = hid[(n0+r)*HID_ + c];
        sm += v; sq += v*v;
    }
    atomicAdd(&bnsum[c], sm);
    atomicAdd(&bnsum[HID_ + c], sq);
}

// ---------------------------------------------------------------------------
// logits = relu(BN(hidden)) @ Mw + Mb; out = log_softmax(logits)
// grid: 32 blocks; 1 thread per row.
// ---------------------------------------------------------------------------
__global__ __launch_bounds__(256) void k_logits(
    const float* __restrict__ hid, const float* __restrict__ bnsum,
    const float* __restrict__ gamma, const float* __restrict__ beta,
    const float* __restrict__ Mw, const float* __restrict__ Mb,
    float* __restrict__ outls)
{
    __shared__ float sc[HID_], sh[HID_], sMb[COUT_];
    __shared__ float sMw[HID_][COUT_];
    const int tid = threadIdx.x;
    {
        const float sm = bnsum[tid], sq = bnsum[HID_+tid];
        const float mu  = sm * (1.0f/N_);
        const float var = sq * (1.0f/N_) - mu*mu;
        const float a   = gamma[tid] * rsqrtf(var + EPS_);
        sc[tid] = a;
        sh[tid] = beta[tid] - mu*a;
    }
    for (int j = tid; j < HID_*COUT_; j += 256)
        sMw[j / COUT_][j % COUT_] = Mw[j];
    if (tid < COUT_) sMb[tid] = Mb[tid];
    __syncthreads();

    const int n = blockIdx.x*256 + tid;
    float acc[COUT_];
    #pragma unroll
    for (int j = 0; j < COUT_; ++j) acc[j] = sMb[j];

    const float4* hrow = reinterpret_cast<const float4*>(hid + n*HID_);
    for (int c4 = 0; c4 < HID_/4; ++c4) {
        const float4 h4 = hrow[c4];
        const float hv[4] = {h4.x, h4.y, h4.z, h4.w};
        #pragma unroll
        for (int q = 0; q < 4; ++q) {
            const int c = 4*c4 + q;
            const float hn = fmaxf(hv[q]*sc[c] + sh[c], 0.f);
            #pragma unroll
            for (int j0 = 0; j0 < COUT_; j0 += 4) {
                const float4 w = *reinterpret_cast<const float4*>(&sMw[c][j0]);
                acc[j0+0] += hn*w.x; acc[j0+1] += hn*w.y;
                acc[j0+2] += hn*w.z; acc[j0+3] += hn*w.w;
            }
        }
    }
    float m = -1e30f;
    #pragma unroll
    for (int j = 0; j < COUT_; ++j) m = fmaxf(m, acc[j]);
    float ssum = 0.f;
    #pragma unroll
    for (int j = 0; j < COUT_; ++j) ssum += expf(acc[j] - m);
    const float lse = logf(ssum);
    #pragma unroll
    for (int j = 0; j < COUT_; ++j)
        outls[n*COUT_ + j] = acc[j] - m - lse;
}

// ---------------------------------------------------------------------------
extern "C" void kernel_launch(void* const* d_in, const int* in_sizes, int n_in,
                              void* d_out, int out_size, void* d_ws, size_t ws_size,
                              hipStream_t stream)
{
    const float* X        = (const float*)d_in[0];
    const float* La       = (const float*)d_in[1];
    const float* U        = (const float*)d_in[2];
    const float* eW1      = (const float*)d_in[3];
    const float* eb1      = (const float*)d_in[4];
    const float* eW2      = (const float*)d_in[5];
    const float* eb2      = (const float*)d_in[6];
    const float* eW3      = (const float*)d_in[7];
    const float* eb3      = (const float*)d_in[8];
    const float* gW1      = (const float*)d_in[9];
    const float* gb1      = (const float*)d_in[10];
    const float* gW2      = (const float*)d_in[11];
    const float* gb2      = (const float*)d_in[12];
    const float* Ww       = (const float*)d_in[13];
    const float* Wb       = (const float*)d_in[14];
    const float* bn_gamma = (const float*)d_in[15];
    const float* bn_beta  = (const float*)d_in[16];
    const float* Mw       = (const float*)d_in[17];
    const float* Mb       = (const float*)d_in[18];

    float* out   = (float*)d_out;
    float* ws    = (float*)d_ws;
    float* Vsum  = ws + WS_VSUM;
    float* bnsum = ws + WS_BNSUM;
    float* T     = ws + WS_T;
    float* s     = ws + WS_S;
    float* G     = ws + WS_G;

    float* outls = out;                 // [8192][40] log_softmax
    float* hid   = out + N_*COUT_;      // [8192][256] hidden (output 1)

    // zero Vsum + bnsum + T (contiguous prefix)
    hipMemsetAsync(ws, 0, (size_t)(WS_T + K_*CIN_) * sizeof(float), stream);

    k_expert<<<dim3(E_, N_/32), 256, 0, stream>>>(U, eW1, eb1, eW2, eb2, eW3, eb3, Vsum);
    k_gate  <<<1, 256, 0, stream>>>(La, gW1, gb1, gW2, gb2, Vsum, s);
    k_ut_x  <<<dim3(16, 16), 256, 0, stream>>>(U, X, T);
    k_g     <<<25, 256, 0, stream>>>(T, Ww, G);
    k_hidden<<<dim3(2, 128), 256, 0, stream>>>(U, s, G, Wb, hid);
    k_bnstat<<<64, 256, 0, stream>>>(hid, bnsum);
    k_logits<<<32, 256, 0, stream>>>(hid, bnsum, bn_gamma, bn_beta, Mw, Mb, outls);
}

// Round 2
// 522.784 us; speedup vs baseline: 2.0190x; 2.0190x over previous
//
#include <hip/hip_runtime.h>
#include <hip/hip_bf16.h>

// Problem constants
#define N_    8192
#define K_    200
#define CIN_  512
#define HID_  256
#define COUT_ 40
#define E_    5
#define MH_   64
#define KG_   40
#define EPS_  1e-5f

// Workspace layout (floats):
#define WS_VSUM  0
#define WS_BNSUM 256
#define WS_T     768
#define WS_S     103168
#define WS_G     103424

typedef __bf16 bf16x8 __attribute__((ext_vector_type(8)));
typedef float  f32x16 __attribute__((ext_vector_type(16)));

__device__ __forceinline__ uint packbf(float a, float b) {
    union { __bf16 h[2]; uint u; } p;
    p.h[0] = (__bf16)a; p.h[1] = (__bf16)b;
    return p.u;
}

union UB { uint4 q; bf16x8 v; };

// ---------------------------------------------------------------------------
// Expert MLP via MFMA.
// v[elem] = W3 . relu(W2^T relu(u*W1+b1) + b2) + b3, summed into Vsum[kg].
// Element space per expert: N_*KG_ = 327680, flat idx = n*KG_ + kg.
// grid: (E_, 320); block 256 = 4 waves; each wave: 4 tiles of 64 elements.
// Per tile: D[g][elem] = sum_h W2[h][g] * h1[elem][h]  (64x64x64)
//   = 2 Mtiles x 2 Ntiles x 4 ksteps of v_mfma_f32_32x32x16_bf16.
// A (W2^T) frags: lane l, mt, t: rows g=mt*32+(l&31), k0=16t+8*(l>>5),
//   reg r = (W2[k0+2r][g], W2[k0+2r+1][g]).  Built once per block.
// B (h1^T) frags via LDS spk[wave][q][elem][j]: u32 = h-pair (8q+2j, 8q+2j+1)
//   of element elem; frag read = ds_read_b128 at [2t+(l>>5)][nt*32+(l&31)].
// C/D: col=lane&31 (elem), row g = mt*32 + (reg&3)+8*(reg>>2)+4*(lane>>5).
// ---------------------------------------------------------------------------
__global__ __launch_bounds__(256) void k_expert(
    const float* __restrict__ U,
    const float* __restrict__ eW1, const float* __restrict__ eb1,
    const float* __restrict__ eW2, const float* __restrict__ eb2,
    const float* __restrict__ eW3, const float* __restrict__ eb3,
    float* __restrict__ Vsum)
{
    const int e   = blockIdx.x;
    const int tid = threadIdx.x;
    const int w   = tid >> 6;        // wave 0..3
    const int l   = tid & 63;        // lane
    const int lo  = l & 31;
    const int hi  = l >> 5;

    __shared__ uint  spk[4][8][64][4];   // 32 KB bf16-packed h1 per wave
    __shared__ float sW1[MH_], sb1[MH_], sb2s[MH_], sW3s[MH_];
    __shared__ float colsum[KG_];

    if (tid < MH_) {
        sW1[tid]  = eW1[e*MH_ + tid];
        sb1[tid]  = eb1[e*MH_ + tid];
        sb2s[tid] = eb2[e*MH_ + tid];
        sW3s[tid] = eW3[e*MH_ + tid];
    }
    if (tid < KG_) colsum[tid] = 0.f;
    const float b3 = eb3[e];

    // Build A fragments (W2^T), 8 frags x 4 VGPRs = 32 VGPRs per lane.
    bf16x8 fa[2][4];
    {
        const float* W2e = eW2 + e*MH_*MH_;
        #pragma unroll
        for (int mt = 0; mt < 2; ++mt) {
            const int grow = mt*32 + lo;
            #pragma unroll
            for (int t = 0; t < 4; ++t) {
                const int k0 = 16*t + 8*hi;
                union { uint u[4]; bf16x8 v; } fb;
                #pragma unroll
                for (int r = 0; r < 4; ++r) {
                    const float x0 = W2e[(k0+2*r  )*MH_ + grow];
                    const float x1 = W2e[(k0+2*r+1)*MH_ + grow];
                    fb.u[r] = packbf(x0, x1);
                }
                fa[mt][t] = fb.v;
            }
        }
    }
    __syncthreads();

    for (int it = 0; it < 4; ++it) {
        const int tile  = (blockIdx.y*16 + it*4 + w);
        const int elem0 = tile * 64;
        const int idx   = elem0 + l;
        const int n     = idx / KG_;
        const int kg    = idx - n*KG_;
        const float u   = U[n*K_ + e*KG_ + kg];

        // h1 = relu(u*W1+b1), packed to bf16 pairs, staged to this wave's LDS
        #pragma unroll
        for (int q = 0; q < 8; ++q) {
            uint wr[4];
            #pragma unroll
            for (int j = 0; j < 4; ++j) {
                const int h = 8*q + 2*j;
                const float a = fmaxf(fmaf(u, sW1[h],   sb1[h]),   0.f);
                const float b = fmaxf(fmaf(u, sW1[h+1], sb1[h+1]), 0.f);
                wr[j] = packbf(a, b);
            }
            *reinterpret_cast<uint4*>(&spk[w][q][l][0]) =
                make_uint4(wr[0], wr[1], wr[2], wr[3]);
        }
        // wave-private region: only need this wave's LDS ops complete
        asm volatile("s_waitcnt lgkmcnt(0)" ::: "memory");

        f32x16 acc00 = {0}; f32x16 acc10 = {0};
        f32x16 acc01 = {0}; f32x16 acc11 = {0};
        #pragma unroll
        for (int t = 0; t < 4; ++t) {
            UB b0, b1;
            b0.q = *reinterpret_cast<const uint4*>(&spk[w][2*t+hi][lo   ][0]);
            b1.q = *reinterpret_cast<const uint4*>(&spk[w][2*t+hi][32+lo][0]);
            acc00 = __builtin_amdgcn_mfma_f32_32x32x16_bf16(fa[0][t], b0.v, acc00, 0, 0, 0);
            acc10 = __builtin_amdgcn_mfma_f32_32x32x16_bf16(fa[1][t], b0.v, acc10, 0, 0, 0);
            acc01 = __builtin_amdgcn_mfma_f32_32x32x16_bf16(fa[0][t], b1.v, acc01, 0, 0, 0);
            acc11 = __builtin_amdgcn_mfma_f32_32x32x16_bf16(fa[1][t], b1.v, acc11, 0, 0, 0);
        }

        // epilogue: v = sum_g relu(D+b2[g])*W3[g], join row-halves, + b3
        float vs0 = 0.f, vs1 = 0.f;
        #pragma unroll
        for (int r = 0; r < 16; ++r) {
            const int gb  = (r & 3) + 8*(r >> 2) + 4*hi;
            const float b2a = sb2s[gb],      w3a = sW3s[gb];
            const float b2b = sb2s[32 + gb], w3b = sW3s[32 + gb];
            vs0 += fmaxf(acc00[r] + b2a, 0.f)*w3a + fmaxf(acc10[r] + b2b, 0.f)*w3b;
            vs1 += fmaxf(acc01[r] + b2a, 0.f)*w3a + fmaxf(acc11[r] + b2b, 0.f)*w3b;
        }
        vs0 += __shfl_xor(vs0, 32);
        vs1 += __shfl_xor(vs1, 32);

        const float myv   = (hi ? vs1 : vs0) + b3;
        const int   myelem = (hi ? 32 : 0) + lo;
        const int   mykg   = (elem0 + myelem) % KG_;
        atomicAdd(&colsum[mykg], myv);
    }

    __syncthreads();
    if (tid < KG_) atomicAdd(&Vsum[e*KG_ + tid], colsum[tid]);
}

// ---------------------------------------------------------------------------
// Gate: stats = mean La per group; g = softmax(relu(stats@gW1+gb1)@gW2+gb2)
// s[k] = g[k/40] * Vsum[k] / N
// ---------------------------------------------------------------------------
__global__ void k_gate(
    const float* __restrict__ La,
    const float* __restrict__ gW1, const float* __restrict__ gb1,
    const float* __restrict__ gW2, const float* __restrict__ gb2,
    const float* __restrict__ Vsum, float* __restrict__ s)
{
    __shared__ float sg[E_];
    const int tid = threadIdx.x;
    if (tid == 0) {
        float stats[E_], g1[E_], g2[E_];
        for (int e = 0; e < E_; ++e) {
            float acc = 0.f;
            for (int k = 0; k < KG_; ++k) acc += La[e*KG_ + k];
            stats[e] = acc * (1.0f/KG_);
        }
        for (int j = 0; j < E_; ++j) {
            float acc = gb1[j];
            for (int i = 0; i < E_; ++i) acc += stats[i]*gW1[i*E_ + j];
            g1[j] = fmaxf(acc, 0.f);
        }
        float m = -1e30f;
        for (int j = 0; j < E_; ++j) {
            float acc = gb2[j];
            for (int i = 0; i < E_; ++i) acc += g1[i]*gW2[i*E_ + j];
            g2[j] = acc;
            m = fmaxf(m, acc);
        }
        float ssum = 0.f;
        for (int j = 0; j < E_; ++j) { g2[j] = expf(g2[j]-m); ssum += g2[j]; }
        for (int j = 0; j < E_; ++j) sg[j] = g2[j] / ssum;
    }
    __syncthreads();
    if (tid < K_) s[tid] = sg[tid / KG_] * Vsum[tid] * (1.0f/N_);
}

// ---------------------------------------------------------------------------
// T = U^T @ X   [200][512]
// grid: (16 ctiles of 32, 16 nsplits of 512); block 256.
// ---------------------------------------------------------------------------
__global__ __launch_bounds__(256) void k_ut_x(
    const float* __restrict__ U, const float* __restrict__ X,
    float* __restrict__ T)
{
    const int c0  = blockIdx.x * 32;
    const int n0  = blockIdx.y * 512;
    const int tid = threadIdx.x;
    const int cl  = tid & 31;
    const int kq  = tid >> 5;

    __shared__ float sU[8][K_];
    __shared__ float sX[8][32];

    float acc[25];
    #pragma unroll
    for (int i = 0; i < 25; ++i) acc[i] = 0.f;

    for (int nb = 0; nb < 512; nb += 8) {
        __syncthreads();
        for (int j = tid; j < 8*K_; j += 256) {
            const int r = j / K_, k = j % K_;
            sU[r][k] = U[(n0+nb+r)*K_ + k];
        }
        sX[kq][cl] = X[(n0+nb+kq)*CIN_ + c0 + cl];
        __syncthreads();
        #pragma unroll
        for (int r = 0; r < 8; ++r) {
            const float xv = sX[r][cl];
            #pragma unroll
            for (int i = 0; i < 25; ++i)
                acc[i] += sU[r][kq + 8*i] * xv;
        }
    }
    #pragma unroll
    for (int i = 0; i < 25; ++i)
        atomicAdd(&T[(kq + 8*i)*CIN_ + c0 + cl], acc[i]);
}

// ---------------------------------------------------------------------------
// G = T @ Ww   [200][256]
// ---------------------------------------------------------------------------
__global__ __launch_bounds__(256) void k_g(
    const float* __restrict__ T, const float* __restrict__ Ww,
    float* __restrict__ G)
{
    const int k0 = blockIdx.x * 8;
    const int c  = threadIdx.x;
    float acc[8];
    #pragma unroll
    for (int r = 0; r < 8; ++r) acc[r] = 0.f;
    for (int ci = 0; ci < CIN_; ++ci) {
        const float w = Ww[ci*HID_ + c];
        #pragma unroll
        for (int r = 0; r < 8; ++r)
            acc[r] += T[(k0+r)*CIN_ + ci] * w;
    }
    #pragma unroll
    for (int r = 0; r < 8; ++r)
        G[(k0+r)*HID_ + c] = acc[r];
}

// ---------------------------------------------------------------------------
// hidden = (U*s) @ G + Wb   [8192][256]
// ---------------------------------------------------------------------------
__global__ __launch_bounds__(256) void k_hidden(
    const float* __restrict__ U, const float* __restrict__ s,
    const float* __restrict__ G, const float* __restrict__ Wb,
    float* __restrict__ hid)
{
    const int c0  = blockIdx.x * 128;
    const int n0  = blockIdx.y * 64;
    const int tid = threadIdx.x;
    const int cl  = tid & 127;
    const int nr  = tid >> 7;          // 0..1

    __shared__ float ss[K_];
    __shared__ float sUs[64][KG_];
    __shared__ float sG[KG_][128];

    if (tid < K_) ss[tid] = s[tid];
    float acc[32];
    #pragma unroll
    for (int i = 0; i < 32; ++i) acc[i] = 0.f;
    __syncthreads();

    for (int k0 = 0; k0 < K_; k0 += KG_) {
        __syncthreads();
        for (int j = tid; j < 64*KG_; j += 256) {
            const int r = j / KG_, kk = j % KG_;
            sUs[r][kk] = U[(n0+r)*K_ + k0 + kk] * ss[k0+kk];
        }
        for (int j = tid; j < KG_*128; j += 256) {
            const int r = j >> 7, cc = j & 127;
            sG[r][cc] = G[(k0+r)*HID_ + c0 + cc];
        }
        __syncthreads();
        #pragma unroll 8
        for (int kk = 0; kk < KG_; ++kk) {
            const float gv = sG[kk][cl];
            #pragma unroll
            for (int i = 0; i < 32; ++i)
                acc[i] += sUs[nr + 2*i][kk] * gv;
        }
    }
    const float wb = Wb[c0 + cl];
    #pragma unroll
    for (int i = 0; i < 32; ++i)
        hid[(n0 + nr + 2*i)*HID_ + c0 + cl] = acc[i] + wb;
}

// ---------------------------------------------------------------------------
// BN batch stats
// ---------------------------------------------------------------------------
__global__ __launch_bounds__(256) void k_bnstat(
    const float* __restrict__ hid, float* __restrict__ bnsum)
{
    const int c  = threadIdx.x;
    const int n0 = blockIdx.x * 128;
    float sm = 0.f, sq = 0.f;
    for (int r = 0; r < 128; ++r) {
        const float v = hid[(n0+r)*HID_ + c];
        sm += v; sq += v*v;
    }
    atomicAdd(&bnsum[c], sm);
    atomicAdd(&bnsum[HID_ + c], sq);
}

// ---------------------------------------------------------------------------
// logits = relu(BN(hidden)) @ Mw + Mb; out = log_softmax(logits)
// ---------------------------------------------------------------------------
__global__ __launch_bounds__(256) void k_logits(
    const float* __restrict__ hid, const float* __restrict__ bnsum,
    const float* __restrict__ gamma, const float* __restrict__ beta,
    const float* __restrict__ Mw, const float* __restrict__ Mb,
    float* __restrict__ outls)
{
    __shared__ float sc[HID_], sh[HID_], sMb[COUT_];
    __shared__ float sMw[HID_][COUT_];
    const int tid = threadIdx.x;
    {
        const float sm = bnsum[tid], sq = bnsum[HID_+tid];
        const float mu  = sm * (1.0f/N_);
        const float var = sq * (1.0f/N_) - mu*mu;
        const float a   = gamma[tid] * rsqrtf(var + EPS_);
        sc[tid] = a;
        sh[tid] = beta[tid] - mu*a;
    }
    for (int j = tid; j < HID_*COUT_; j += 256)
        sMw[j / COUT_][j % COUT_] = Mw[j];
    if (tid < COUT_) sMb[tid] = Mb[tid];
    __syncthreads();

    const int n = blockIdx.x*256 + tid;
    float acc[COUT_];
    #pragma unroll
    for (int j = 0; j < COUT_; ++j) acc[j] = sMb[j];

    const float4* hrow = reinterpret_cast<const float4*>(hid + n*HID_);
    for (int c4 = 0; c4 < HID_/4; ++c4) {
        const float4 h4 = hrow[c4];
        const float hv[4] = {h4.x, h4.y, h4.z, h4.w};
        #pragma unroll
        for (int q = 0; q < 4; ++q) {
            const int c = 4*c4 + q;
            const float hn = fmaxf(hv[q]*sc[c] + sh[c], 0.f);
            #pragma unroll
            for (int j0 = 0; j0 < COUT_; j0 += 4) {
                const float4 wv = *reinterpret_cast<const float4*>(&sMw[c][j0]);
                acc[j0+0] += hn*wv.x; acc[j0+1] += hn*wv.y;
                acc[j0+2] += hn*wv.z; acc[j0+3] += hn*wv.w;
            }
        }
    }
    float m = -1e30f;
    #pragma unroll
    for (int j = 0; j < COUT_; ++j) m = fmaxf(m, acc[j]);
    float ssum = 0.f;
    #pragma unroll
    for (int j = 0; j < COUT_; ++j) ssum += expf(acc[j] - m);
    const float lse = logf(ssum);
    #pragma unroll
    for (int j = 0; j < COUT_; ++j)
        outls[n*COUT_ + j] = acc[j] - m - lse;
}

// ---------------------------------------------------------------------------
extern "C" void kernel_launch(void* const* d_in, const int* in_sizes, int n_in,
                              void* d_out, int out_size, void* d_ws, size_t ws_size,
                              hipStream_t stream)
{
    const float* X        = (const float*)d_in[0];
    const float* La       = (const float*)d_in[1];
    const float* U        = (const float*)d_in[2];
    const float* eW1      = (const float*)d_in[3];
    const float* eb1      = (const float*)d_in[4];
    const float* eW2      = (const float*)d_in[5];
    const float* eb2      = (const float*)d_in[6];
    const float* eW3      = (const float*)d_in[7];
    const float* eb3      = (const float*)d_in[8];
    const float* gW1      = (const float*)d_in[9];
    const float* gb1      = (const float*)d_in[10];
    const float* gW2      = (const float*)d_in[11];
    const float* gb2      = (const float*)d_in[12];
    const float* Ww       = (const float*)d_in[13];
    const float* Wb       = (const float*)d_in[14];
    const float* bn_gamma = (const float*)d_in[15];
    const float* bn_beta  = (const float*)d_in[16];
    const float* Mw       = (const float*)d_in[17];
    const float* Mb       = (const float*)d_in[18];

    float* out   = (float*)d_out;
    float* ws    = (float*)d_ws;
    float* Vsum  = ws + WS_VSUM;
    float* bnsum = ws + WS_BNSUM;
    float* T     = ws + WS_T;
    float* s     = ws + WS_S;
    float* G     = ws + WS_G;

    float* outls = out;                 // [8192][40] log_softmax
    float* hid   = out + N_*COUT_;      // [8192][256] hidden (output 1)

    // zero Vsum + bnsum + T (contiguous prefix)
    hipMemsetAsync(ws, 0, (size_t)(WS_T + K_*CIN_) * sizeof(float), stream);

    k_expert<<<dim3(E_, 320), 256, 0, stream>>>(U, eW1, eb1, eW2, eb2, eW3, eb3, Vsum);
    k_gate  <<<1, 256, 0, stream>>>(La, gW1, gb1, gW2, gb2, Vsum, s);
    k_ut_x  <<<dim3(16, 16), 256, 0, stream>>>(U, X, T);
    k_g     <<<25, 256, 0, stream>>>(T, Ww, G);
    k_hidden<<<dim3(2, 128), 256, 0, stream>>>(U, s, G, Wb, hid);
    k_bnstat<<<64, 256, 0, stream>>>(hid, bnsum);
    k_logits<<<32, 256, 0, stream>>>(hid, bnsum, bn_gamma, bn_beta, Mw, Mb, outls);
}

// Round 3
// 280.013 us; speedup vs baseline: 3.7694x; 1.8670x over previous
//
#include <hip/hip_runtime.h>
#include <hip/hip_bf16.h>

// Problem constants
#define N_    8192
#define K_    200
#define CIN_  512
#define HID_  256
#define COUT_ 40
#define E_    5
#define MH_   64
#define KG_   40
#define EPS_  1e-5f

// Workspace layout (floats):
#define WS_VSUM  0
#define WS_BNSUM 256
#define WS_T     768
#define WS_S     103168
#define WS_G     103424

#define KSPLIT_ 16   // k_utx reduction splits (P partials live in d_out scratch)

typedef __bf16 bf16x8 __attribute__((ext_vector_type(8)));
typedef float  f32x16 __attribute__((ext_vector_type(16)));

__device__ __forceinline__ uint packbf(float a, float b) {
    union { __bf16 h[2]; uint u; } p;
    p.h[0] = (__bf16)a; p.h[1] = (__bf16)b;
    return p.u;
}

union UB { uint4 q; bf16x8 v; };

// ---------------------------------------------------------------------------
// Expert MLP via MFMA (verified round 2).
// ---------------------------------------------------------------------------
__global__ __launch_bounds__(256) void k_expert(
    const float* __restrict__ U,
    const float* __restrict__ eW1, const float* __restrict__ eb1,
    const float* __restrict__ eW2, const float* __restrict__ eb2,
    const float* __restrict__ eW3, const float* __restrict__ eb3,
    float* __restrict__ Vsum)
{
    const int e   = blockIdx.x;
    const int tid = threadIdx.x;
    const int w   = tid >> 6;        // wave 0..3
    const int l   = tid & 63;        // lane
    const int lo  = l & 31;
    const int hi  = l >> 5;

    __shared__ uint  spk[4][8][64][4];   // 32 KB bf16-packed h1 per wave
    __shared__ float sW1[MH_], sb1[MH_], sb2s[MH_], sW3s[MH_];
    __shared__ float colsum[KG_];

    if (tid < MH_) {
        sW1[tid]  = eW1[e*MH_ + tid];
        sb1[tid]  = eb1[e*MH_ + tid];
        sb2s[tid] = eb2[e*MH_ + tid];
        sW3s[tid] = eW3[e*MH_ + tid];
    }
    if (tid < KG_) colsum[tid] = 0.f;
    const float b3 = eb3[e];

    // A fragments (W2^T), 8 frags x 4 VGPRs.
    bf16x8 fa[2][4];
    {
        const float* W2e = eW2 + e*MH_*MH_;
        #pragma unroll
        for (int mt = 0; mt < 2; ++mt) {
            const int grow = mt*32 + lo;
            #pragma unroll
            for (int t = 0; t < 4; ++t) {
                const int k0 = 16*t + 8*hi;
                union { uint u[4]; bf16x8 v; } fb;
                #pragma unroll
                for (int r = 0; r < 4; ++r) {
                    const float x0 = W2e[(k0+2*r  )*MH_ + grow];
                    const float x1 = W2e[(k0+2*r+1)*MH_ + grow];
                    fb.u[r] = packbf(x0, x1);
                }
                fa[mt][t] = fb.v;
            }
        }
    }
    __syncthreads();

    for (int it = 0; it < 4; ++it) {
        const int tile  = (blockIdx.y*16 + it*4 + w);
        const int elem0 = tile * 64;
        const int idx   = elem0 + l;
        const int n     = idx / KG_;
        const int kg    = idx - n*KG_;
        const float u   = U[n*K_ + e*KG_ + kg];

        #pragma unroll
        for (int q = 0; q < 8; ++q) {
            uint wr[4];
            #pragma unroll
            for (int j = 0; j < 4; ++j) {
                const int h = 8*q + 2*j;
                const float a = fmaxf(fmaf(u, sW1[h],   sb1[h]),   0.f);
                const float b = fmaxf(fmaf(u, sW1[h+1], sb1[h+1]), 0.f);
                wr[j] = packbf(a, b);
            }
            *reinterpret_cast<uint4*>(&spk[w][q][l][0]) =
                make_uint4(wr[0], wr[1], wr[2], wr[3]);
        }
        asm volatile("s_waitcnt lgkmcnt(0)" ::: "memory");

        f32x16 acc00 = {0}; f32x16 acc10 = {0};
        f32x16 acc01 = {0}; f32x16 acc11 = {0};
        #pragma unroll
        for (int t = 0; t < 4; ++t) {
            UB b0, b1;
            b0.q = *reinterpret_cast<const uint4*>(&spk[w][2*t+hi][lo   ][0]);
            b1.q = *reinterpret_cast<const uint4*>(&spk[w][2*t+hi][32+lo][0]);
            acc00 = __builtin_amdgcn_mfma_f32_32x32x16_bf16(fa[0][t], b0.v, acc00, 0, 0, 0);
            acc10 = __builtin_amdgcn_mfma_f32_32x32x16_bf16(fa[1][t], b0.v, acc10, 0, 0, 0);
            acc01 = __builtin_amdgcn_mfma_f32_32x32x16_bf16(fa[0][t], b1.v, acc01, 0, 0, 0);
            acc11 = __builtin_amdgcn_mfma_f32_32x32x16_bf16(fa[1][t], b1.v, acc11, 0, 0, 0);
        }

        float vs0 = 0.f, vs1 = 0.f;
        #pragma unroll
        for (int r = 0; r < 16; ++r) {
            const int gb  = (r & 3) + 8*(r >> 2) + 4*hi;
            const float b2a = sb2s[gb],      w3a = sW3s[gb];
            const float b2b = sb2s[32 + gb], w3b = sW3s[32 + gb];
            vs0 += fmaxf(acc00[r] + b2a, 0.f)*w3a + fmaxf(acc10[r] + b2b, 0.f)*w3b;
            vs1 += fmaxf(acc01[r] + b2a, 0.f)*w3a + fmaxf(acc11[r] + b2b, 0.f)*w3b;
        }
        vs0 += __shfl_xor(vs0, 32);
        vs1 += __shfl_xor(vs1, 32);

        const float myv    = (hi ? vs1 : vs0) + b3;
        const int   myelem = (hi ? 32 : 0) + lo;
        const int   mykg   = (elem0 + myelem) % KG_;
        atomicAdd(&colsum[mykg], myv);
    }

    __syncthreads();
    if (tid < KG_) atomicAdd(&Vsum[e*KG_ + tid], colsum[tid]);
}

// ---------------------------------------------------------------------------
// Gate (unchanged)
// ---------------------------------------------------------------------------
__global__ void k_gate(
    const float* __restrict__ La,
    const float* __restrict__ gW1, const float* __restrict__ gb1,
    const float* __restrict__ gW2, const float* __restrict__ gb2,
    const float* __restrict__ Vsum, float* __restrict__ s)
{
    __shared__ float sg[E_];
    const int tid = threadIdx.x;
    if (tid == 0) {
        float stats[E_], g1[E_], g2[E_];
        for (int e = 0; e < E_; ++e) {
            float acc = 0.f;
            for (int k = 0; k < KG_; ++k) acc += La[e*KG_ + k];
            stats[e] = acc * (1.0f/KG_);
        }
        for (int j = 0; j < E_; ++j) {
            float acc = gb1[j];
            for (int i = 0; i < E_; ++i) acc += stats[i]*gW1[i*E_ + j];
            g1[j] = fmaxf(acc, 0.f);
        }
        float m = -1e30f;
        for (int j = 0; j < E_; ++j) {
            float acc = gb2[j];
            for (int i = 0; i < E_; ++i) acc += g1[i]*gW2[i*E_ + j];
            g2[j] = acc;
            m = fmaxf(m, acc);
        }
        float ssum = 0.f;
        for (int j = 0; j < E_; ++j) { g2[j] = expf(g2[j]-m); ssum += g2[j]; }
        for (int j = 0; j < E_; ++j) sg[j] = g2[j] / ssum;
    }
    __syncthreads();
    if (tid < K_) s[tid] = sg[tid / KG_] * Vsum[tid] * (1.0f/N_);
}

// ---------------------------------------------------------------------------
// P[ks] += partial of T = U^T X via MFMA (bf16 inputs, fp32 acc).
// C[m][c]: m = k-index (M=200 pad 224/256), c = col. Reduction r = node dim.
// grid (16 ctiles of 32 cols, KSPLIT_ ksplits of 512 rows); block 256 = 4 waves.
// Wave w owns mtiles {2w, 2w+1} (mt 7 computed on garbage, discarded).
// LDS pair-packed rp-major: spkU[rp][m]: u32 = (U[rb+2rp][m], U[rb+2rp+1][m]).
// Frag (t, reg): rp = 8t+4hi+reg -> k = 16t+8hi+2reg(+1)  (k_expert convention)
// C/D: col = lane&31, row = mt*32 + (reg&3)+8*(reg>>2)+4*hi (verified map).
// ---------------------------------------------------------------------------
__global__ __launch_bounds__(256) void k_utx(
    const float* __restrict__ U, const float* __restrict__ X,
    float* __restrict__ P)
{
    const int c0  = blockIdx.x * 32;
    const int ks  = blockIdx.y;
    const int r0  = ks * 512;
    const int tid = threadIdx.x;
    const int w   = tid >> 6;
    const int l   = tid & 63;
    const int lo  = l & 31;
    const int hi  = l >> 5;

    __shared__ uint spkU[16][256];   // 16 KB
    __shared__ uint spkX[16][32];    //  2 KB

    f32x16 acc[2] = {{0}, {0}};

    for (int it = 0; it < 16; ++it) {
        const int rb = r0 + it*32;
        __syncthreads();
        // stage U pairs: 800 units (50 k4 x 16 rp), coalesced f4 reads
        for (int j = tid; j < 800; j += 256) {
            const int k4 = j % 50, rp = j / 50;
            const float4 a = *reinterpret_cast<const float4*>(&U[(rb + 2*rp    )*K_ + 4*k4]);
            const float4 b = *reinterpret_cast<const float4*>(&U[(rb + 2*rp + 1)*K_ + 4*k4]);
            uint4 pk;
            pk.x = packbf(a.x, b.x); pk.y = packbf(a.y, b.y);
            pk.z = packbf(a.z, b.z); pk.w = packbf(a.w, b.w);
            *reinterpret_cast<uint4*>(&spkU[rp][4*k4]) = pk;
        }
        // stage X pairs: 128 units (8 c4 x 16 rp)
        if (tid < 128) {
            const int c4 = tid % 8, rp = tid / 8;
            const float4 a = *reinterpret_cast<const float4*>(&X[(rb + 2*rp    )*CIN_ + c0 + 4*c4]);
            const float4 b = *reinterpret_cast<const float4*>(&X[(rb + 2*rp + 1)*CIN_ + c0 + 4*c4]);
            uint4 pk;
            pk.x = packbf(a.x, b.x); pk.y = packbf(a.y, b.y);
            pk.z = packbf(a.z, b.z); pk.w = packbf(a.w, b.w);
            *reinterpret_cast<uint4*>(&spkX[rp][4*c4]) = pk;
        }
        __syncthreads();

        #pragma unroll
        for (int t = 0; t < 2; ++t) {
            UB bx;
            bx.q.x = spkX[8*t + 4*hi + 0][lo];
            bx.q.y = spkX[8*t + 4*hi + 1][lo];
            bx.q.z = spkX[8*t + 4*hi + 2][lo];
            bx.q.w = spkX[8*t + 4*hi + 3][lo];
            #pragma unroll
            for (int m = 0; m < 2; ++m) {
                const int mrow = (2*w + m)*32 + lo;
                UB ax;
                ax.q.x = spkU[8*t + 4*hi + 0][mrow];
                ax.q.y = spkU[8*t + 4*hi + 1][mrow];
                ax.q.z = spkU[8*t + 4*hi + 2][mrow];
                ax.q.w = spkU[8*t + 4*hi + 3][mrow];
                acc[m] = __builtin_amdgcn_mfma_f32_32x32x16_bf16(ax.v, bx.v, acc[m], 0, 0, 0);
            }
        }
    }

    // epilogue: write valid rows m < 200 of this ksplit's partial
    #pragma unroll
    for (int m = 0; m < 2; ++m) {
        const int mt = 2*w + m;
        #pragma unroll
        for (int r = 0; r < 16; ++r) {
            const int mm = mt*32 + (r & 3) + 8*(r >> 2) + 4*hi;
            if (mm < K_)
                P[(ks*K_ + mm)*CIN_ + c0 + lo] = acc[m][r];
        }
    }
}

// ---------------------------------------------------------------------------
// T = sum_ks P[ks]   (200x512)
// ---------------------------------------------------------------------------
__global__ __launch_bounds__(256) void k_red(
    const float* __restrict__ P, float* __restrict__ T)
{
    const int j = blockIdx.x*256 + threadIdx.x;   // f4 index < 25600
    float4 s = {0.f, 0.f, 0.f, 0.f};
    for (int ks = 0; ks < KSPLIT_; ++ks) {
        const float4 v = *reinterpret_cast<const float4*>(&P[ks*K_*CIN_ + j*4]);
        s.x += v.x; s.y += v.y; s.z += v.z; s.w += v.w;
    }
    *reinterpret_cast<float4*>(&T[j*4]) = s;
}

// ---------------------------------------------------------------------------
// G = T @ Ww   [200][256]; grid 50 blocks of 4 k-rows; thread = output col.
// ---------------------------------------------------------------------------
__global__ __launch_bounds__(256) void k_g(
    const float* __restrict__ T, const float* __restrict__ Ww,
    float* __restrict__ G)
{
    const int k0  = blockIdx.x * 4;
    const int c   = threadIdx.x;
    __shared__ float4 sT4[4][128];

    for (int j = threadIdx.x; j < 512; j += 256) {
        const int r = j >> 7, c4 = j & 127;
        sT4[r][c4] = reinterpret_cast<const float4*>(T)[(k0+r)*128 + c4];
    }
    __syncthreads();

    float a0 = 0.f, a1 = 0.f, a2 = 0.f, a3 = 0.f;
    for (int ci4 = 0; ci4 < 128; ++ci4) {
        const float w0 = Ww[(4*ci4+0)*HID_ + c];
        const float w1 = Ww[(4*ci4+1)*HID_ + c];
        const float w2 = Ww[(4*ci4+2)*HID_ + c];
        const float w3 = Ww[(4*ci4+3)*HID_ + c];
        float4 t;
        t = sT4[0][ci4]; a0 += t.x*w0 + t.y*w1 + t.z*w2 + t.w*w3;
        t = sT4[1][ci4]; a1 += t.x*w0 + t.y*w1 + t.z*w2 + t.w*w3;
        t = sT4[2][ci4]; a2 += t.x*w0 + t.y*w1 + t.z*w2 + t.w*w3;
        t = sT4[3][ci4]; a3 += t.x*w0 + t.y*w1 + t.z*w2 + t.w*w3;
    }
    G[(k0+0)*HID_ + c] = a0;
    G[(k0+1)*HID_ + c] = a1;
    G[(k0+2)*HID_ + c] = a2;
    G[(k0+3)*HID_ + c] = a3;
}

// ---------------------------------------------------------------------------
// hidden = (U*s) @ G + Wb   [8192][256] (fp32; vectorized LDS reads)
// ---------------------------------------------------------------------------
__global__ __launch_bounds__(256) void k_hidden(
    const float* __restrict__ U, const float* __restrict__ s,
    const float* __restrict__ G, const float* __restrict__ Wb,
    float* __restrict__ hid)
{
    const int c0  = blockIdx.x * 128;
    const int n0  = blockIdx.y * 64;
    const int tid = threadIdx.x;
    const int cl  = tid & 127;
    const int nr  = tid >> 7;          // 0..1

    __shared__ float ss[K_];
    __shared__ float sUs[64][KG_];     // [64][40]
    __shared__ float sG[KG_][128];

    if (tid < K_) ss[tid] = s[tid];
    float acc[32];
    #pragma unroll
    for (int i = 0; i < 32; ++i) acc[i] = 0.f;
    __syncthreads();

    for (int k0 = 0; k0 < K_; k0 += KG_) {
        __syncthreads();
        // stage sUs: 640 f4 (64 rows x 10 k4)
        for (int j = tid; j < 640; j += 256) {
            const int r = j / 10, k4 = j % 10;
            float4 u4 = *reinterpret_cast<const float4*>(&U[(n0+r)*K_ + k0 + 4*k4]);
            u4.x *= ss[k0 + 4*k4 + 0];
            u4.y *= ss[k0 + 4*k4 + 1];
            u4.z *= ss[k0 + 4*k4 + 2];
            u4.w *= ss[k0 + 4*k4 + 3];
            *reinterpret_cast<float4*>(&sUs[r][4*k4]) = u4;
        }
        // stage sG: 1280 f4 (40 rows x 32 c4)
        for (int j = tid; j < 1280; j += 256) {
            const int r = j >> 5, c4 = j & 31;
            *reinterpret_cast<float4*>(&sG[r][4*c4]) =
                *reinterpret_cast<const float4*>(&G[(k0+r)*HID_ + c0 + 4*c4]);
        }
        __syncthreads();
        #pragma unroll
        for (int k4 = 0; k4 < 10; ++k4) {
            const float g0 = sG[4*k4+0][cl];
            const float g1 = sG[4*k4+1][cl];
            const float g2 = sG[4*k4+2][cl];
            const float g3 = sG[4*k4+3][cl];
            #pragma unroll
            for (int i = 0; i < 32; ++i) {
                const float4 u4 = *reinterpret_cast<const float4*>(&sUs[nr + 2*i][4*k4]);
                acc[i] += u4.x*g0 + u4.y*g1 + u4.z*g2 + u4.w*g3;
            }
        }
    }
    const float wb = Wb[c0 + cl];
    #pragma unroll
    for (int i = 0; i < 32; ++i)
        hid[(n0 + nr + 2*i)*HID_ + c0 + cl] = acc[i] + wb;
}

// ---------------------------------------------------------------------------
// BN batch stats (grid 256 x 32 rows)
// ---------------------------------------------------------------------------
__global__ __launch_bounds__(256) void k_bnstat(
    const float* __restrict__ hid, float* __restrict__ bnsum)
{
    const int c  = threadIdx.x;
    const int n0 = blockIdx.x * 32;
    float sm = 0.f, sq = 0.f;
    for (int r = 0; r < 32; ++r) {
        const float v = hid[(n0+r)*HID_ + c];
        sm += v; sq += v*v;
    }
    atomicAdd(&bnsum[c], sm);
    atomicAdd(&bnsum[HID_ + c], sq);
}

// ---------------------------------------------------------------------------
// logits = relu(BN(hidden)) @ Mw + Mb; out = log_softmax.
// grid 64; block 256 = 128 rows x 2 column-halves; LDS combine.
// ---------------------------------------------------------------------------
__global__ __launch_bounds__(256) void k_logits(
    const float* __restrict__ hid, const float* __restrict__ bnsum,
    const float* __restrict__ gamma, const float* __restrict__ beta,
    const float* __restrict__ Mw, const float* __restrict__ Mb,
    float* __restrict__ outls)
{
    __shared__ float sc[HID_], sh[HID_], sMb[COUT_];
    __shared__ float sMw[HID_][COUT_];        // 40 KB
    __shared__ float sPart[128][COUT_ + 1];   // ~20.5 KB

    const int tid  = threadIdx.x;
    const int rloc = tid & 127;
    const int half = tid >> 7;
    const int n    = blockIdx.x*128 + rloc;

    {
        const float sm = bnsum[tid], sq = bnsum[HID_+tid];
        const float mu  = sm * (1.0f/N_);
        const float var = sq * (1.0f/N_) - mu*mu;
        const float a   = gamma[tid] * rsqrtf(var + EPS_);
        sc[tid] = a;
        sh[tid] = beta[tid] - mu*a;
    }
    for (int j = tid; j < HID_*COUT_/4; j += 256)
        reinterpret_cast<float4*>(&sMw[0][0])[j] = reinterpret_cast<const float4*>(Mw)[j];
    if (tid < COUT_) sMb[tid] = Mb[tid];
    __syncthreads();

    float acc[COUT_];
    #pragma unroll
    for (int j = 0; j < COUT_; ++j) acc[j] = half ? 0.f : sMb[j];

    const int cbase = half * 128;
    const float4* hrow = reinterpret_cast<const float4*>(&hid[n*HID_ + cbase]);
    for (int c4 = 0; c4 < 32; ++c4) {
        const float4 h4 = hrow[c4];
        const float hv[4] = {h4.x, h4.y, h4.z, h4.w};
        #pragma unroll
        for (int q = 0; q < 4; ++q) {
            const int c = cbase + 4*c4 + q;
            const float hn = fmaxf(hv[q]*sc[c] + sh[c], 0.f);
            #pragma unroll
            for (int j0 = 0; j0 < COUT_; j0 += 4) {
                const float4 wv = *reinterpret_cast<const float4*>(&sMw[c][j0]);
                acc[j0+0] += hn*wv.x; acc[j0+1] += hn*wv.y;
                acc[j0+2] += hn*wv.z; acc[j0+3] += hn*wv.w;
            }
        }
    }
    if (half) {
        #pragma unroll
        for (int j = 0; j < COUT_; ++j) sPart[rloc][j] = acc[j];
    }
    __syncthreads();
    if (!half) {
        #pragma unroll
        for (int j = 0; j < COUT_; ++j) acc[j] += sPart[rloc][j];
        float m = -1e30f;
        #pragma unroll
        for (int j = 0; j < COUT_; ++j) m = fmaxf(m, acc[j]);
        float ssum = 0.f;
        #pragma unroll
        for (int j = 0; j < COUT_; ++j) ssum += expf(acc[j] - m);
        const float lse = m + logf(ssum);
        #pragma unroll
        for (int j = 0; j < COUT_; ++j)
            outls[n*COUT_ + j] = acc[j] - lse;
    }
}

// ---------------------------------------------------------------------------
extern "C" void kernel_launch(void* const* d_in, const int* in_sizes, int n_in,
                              void* d_out, int out_size, void* d_ws, size_t ws_size,
                              hipStream_t stream)
{
    const float* X        = (const float*)d_in[0];
    const float* La       = (const float*)d_in[1];
    const float* U        = (const float*)d_in[2];
    const float* eW1      = (const float*)d_in[3];
    const float* eb1      = (const float*)d_in[4];
    const float* eW2      = (const float*)d_in[5];
    const float* eb2      = (const float*)d_in[6];
    const float* eW3      = (const float*)d_in[7];
    const float* eb3      = (const float*)d_in[8];
    const float* gW1      = (const float*)d_in[9];
    const float* gb1      = (const float*)d_in[10];
    const float* gW2      = (const float*)d_in[11];
    const float* gb2      = (const float*)d_in[12];
    const float* Ww       = (const float*)d_in[13];
    const float* Wb       = (const float*)d_in[14];
    const float* bn_gamma = (const float*)d_in[15];
    const float* bn_beta  = (const float*)d_in[16];
    const float* Mw       = (const float*)d_in[17];
    const float* Mb       = (const float*)d_in[18];

    float* out   = (float*)d_out;
    float* ws    = (float*)d_ws;
    float* Vsum  = ws + WS_VSUM;
    float* bnsum = ws + WS_BNSUM;
    float* T     = ws + WS_T;
    float* s     = ws + WS_S;
    float* G     = ws + WS_G;

    float* outls = out;                 // [8192][40] log_softmax (written LAST)
    float* hid   = out + N_*COUT_;      // [8192][256] hidden (output 1)
    float* P     = out;                 // d_out reused as scratch for k_utx
                                        // partials (6.55 MB < 9.7 MB), fully
                                        // consumed by k_red before k_hidden.

    // zero Vsum + bnsum (atomic accumulators)
    hipMemsetAsync(ws, 0, (size_t)768 * sizeof(float), stream);

    k_utx   <<<dim3(16, KSPLIT_), 256, 0, stream>>>(U, X, P);
    k_expert<<<dim3(E_, 320),     256, 0, stream>>>(U, eW1, eb1, eW2, eb2, eW3, eb3, Vsum);
    k_gate  <<<1,   256, 0, stream>>>(La, gW1, gb1, gW2, gb2, Vsum, s);
    k_red   <<<100, 256, 0, stream>>>(P, T);
    k_g     <<<50,  256, 0, stream>>>(T, Ww, G);
    k_hidden<<<dim3(2, 128), 256, 0, stream>>>(U, s, G, Wb, hid);
    k_bnstat<<<256, 256, 0, stream>>>(hid, bnsum);
    k_logits<<<64,  256, 0, stream>>>(hid, bnsum, bn_gamma, bn_beta, Mw, Mb, outls);
}

// Round 4
// 245.061 us; speedup vs baseline: 4.3070x; 1.1426x over previous
//
#include <hip/hip_runtime.h>
#include <hip/hip_bf16.h>

// Problem constants
#define N_    8192
#define K_    200
#define CIN_  512
#define HID_  256
#define COUT_ 40
#define E_    5
#define MH_   64
#define KG_   40
#define EPS_  1e-5f

// Workspace layout (floats):
#define WS_VSUM  0
#define WS_BNSUM 256
#define WS_T     768
#define WS_S     103168
#define WS_G     103424

#define KSPLIT_ 16   // k_utx reduction splits (P partials live in d_out scratch)

typedef __bf16 bf16x8 __attribute__((ext_vector_type(8)));
typedef float  f32x16 __attribute__((ext_vector_type(16)));

__device__ __forceinline__ uint packbf(float a, float b) {
    union { __bf16 h[2]; uint u; } p;
    p.h[0] = (__bf16)a; p.h[1] = (__bf16)b;
    return p.u;
}

union UB { uint4 q; bf16x8 v; };

// ---------------------------------------------------------------------------
// Expert MLP via MFMA (verified rounds 2-3; unchanged).
// ---------------------------------------------------------------------------
__global__ __launch_bounds__(256) void k_expert(
    const float* __restrict__ U,
    const float* __restrict__ eW1, const float* __restrict__ eb1,
    const float* __restrict__ eW2, const float* __restrict__ eb2,
    const float* __restrict__ eW3, const float* __restrict__ eb3,
    float* __restrict__ Vsum)
{
    const int e   = blockIdx.x;
    const int tid = threadIdx.x;
    const int w   = tid >> 6;        // wave 0..3
    const int l   = tid & 63;        // lane
    const int lo  = l & 31;
    const int hi  = l >> 5;

    __shared__ uint  spk[4][8][64][4];   // 32 KB bf16-packed h1 per wave
    __shared__ float sW1[MH_], sb1[MH_], sb2s[MH_], sW3s[MH_];
    __shared__ float colsum[KG_];

    if (tid < MH_) {
        sW1[tid]  = eW1[e*MH_ + tid];
        sb1[tid]  = eb1[e*MH_ + tid];
        sb2s[tid] = eb2[e*MH_ + tid];
        sW3s[tid] = eW3[e*MH_ + tid];
    }
    if (tid < KG_) colsum[tid] = 0.f;
    const float b3 = eb3[e];

    // A fragments (W2^T), 8 frags x 4 VGPRs.
    bf16x8 fa[2][4];
    {
        const float* W2e = eW2 + e*MH_*MH_;
        #pragma unroll
        for (int mt = 0; mt < 2; ++mt) {
            const int grow = mt*32 + lo;
            #pragma unroll
            for (int t = 0; t < 4; ++t) {
                const int k0 = 16*t + 8*hi;
                union { uint u[4]; bf16x8 v; } fb;
                #pragma unroll
                for (int r = 0; r < 4; ++r) {
                    const float x0 = W2e[(k0+2*r  )*MH_ + grow];
                    const float x1 = W2e[(k0+2*r+1)*MH_ + grow];
                    fb.u[r] = packbf(x0, x1);
                }
                fa[mt][t] = fb.v;
            }
        }
    }
    __syncthreads();

    for (int it = 0; it < 4; ++it) {
        const int tile  = (blockIdx.y*16 + it*4 + w);
        const int elem0 = tile * 64;
        const int idx   = elem0 + l;
        const int n     = idx / KG_;
        const int kg    = idx - n*KG_;
        const float u   = U[n*K_ + e*KG_ + kg];

        #pragma unroll
        for (int q = 0; q < 8; ++q) {
            uint wr[4];
            #pragma unroll
            for (int j = 0; j < 4; ++j) {
                const int h = 8*q + 2*j;
                const float a = fmaxf(fmaf(u, sW1[h],   sb1[h]),   0.f);
                const float b = fmaxf(fmaf(u, sW1[h+1], sb1[h+1]), 0.f);
                wr[j] = packbf(a, b);
            }
            *reinterpret_cast<uint4*>(&spk[w][q][l][0]) =
                make_uint4(wr[0], wr[1], wr[2], wr[3]);
        }
        asm volatile("s_waitcnt lgkmcnt(0)" ::: "memory");

        f32x16 acc00 = {0}; f32x16 acc10 = {0};
        f32x16 acc01 = {0}; f32x16 acc11 = {0};
        #pragma unroll
        for (int t = 0; t < 4; ++t) {
            UB b0, b1;
            b0.q = *reinterpret_cast<const uint4*>(&spk[w][2*t+hi][lo   ][0]);
            b1.q = *reinterpret_cast<const uint4*>(&spk[w][2*t+hi][32+lo][0]);
            acc00 = __builtin_amdgcn_mfma_f32_32x32x16_bf16(fa[0][t], b0.v, acc00, 0, 0, 0);
            acc10 = __builtin_amdgcn_mfma_f32_32x32x16_bf16(fa[1][t], b0.v, acc10, 0, 0, 0);
            acc01 = __builtin_amdgcn_mfma_f32_32x32x16_bf16(fa[0][t], b1.v, acc01, 0, 0, 0);
            acc11 = __builtin_amdgcn_mfma_f32_32x32x16_bf16(fa[1][t], b1.v, acc11, 0, 0, 0);
        }

        float vs0 = 0.f, vs1 = 0.f;
        #pragma unroll
        for (int r = 0; r < 16; ++r) {
            const int gb  = (r & 3) + 8*(r >> 2) + 4*hi;
            const float b2a = sb2s[gb],      w3a = sW3s[gb];
            const float b2b = sb2s[32 + gb], w3b = sW3s[32 + gb];
            vs0 += fmaxf(acc00[r] + b2a, 0.f)*w3a + fmaxf(acc10[r] + b2b, 0.f)*w3b;
            vs1 += fmaxf(acc01[r] + b2a, 0.f)*w3a + fmaxf(acc11[r] + b2b, 0.f)*w3b;
        }
        vs0 += __shfl_xor(vs0, 32);
        vs1 += __shfl_xor(vs1, 32);

        const float myv    = (hi ? vs1 : vs0) + b3;
        const int   myelem = (hi ? 32 : 0) + lo;
        const int   mykg   = (elem0 + myelem) % KG_;
        atomicAdd(&colsum[mykg], myv);
    }

    __syncthreads();
    if (tid < KG_) atomicAdd(&Vsum[e*KG_ + tid], colsum[tid]);
}

// ---------------------------------------------------------------------------
// Gate (unchanged)
// ---------------------------------------------------------------------------
__global__ void k_gate(
    const float* __restrict__ La,
    const float* __restrict__ gW1, const float* __restrict__ gb1,
    const float* __restrict__ gW2, const float* __restrict__ gb2,
    const float* __restrict__ Vsum, float* __restrict__ s)
{
    __shared__ float sg[E_];
    const int tid = threadIdx.x;
    if (tid == 0) {
        float stats[E_], g1[E_], g2[E_];
        for (int e = 0; e < E_; ++e) {
            float acc = 0.f;
            for (int k = 0; k < KG_; ++k) acc += La[e*KG_ + k];
            stats[e] = acc * (1.0f/KG_);
        }
        for (int j = 0; j < E_; ++j) {
            float acc = gb1[j];
            for (int i = 0; i < E_; ++i) acc += stats[i]*gW1[i*E_ + j];
            g1[j] = fmaxf(acc, 0.f);
        }
        float m = -1e30f;
        for (int j = 0; j < E_; ++j) {
            float acc = gb2[j];
            for (int i = 0; i < E_; ++i) acc += g1[i]*gW2[i*E_ + j];
            g2[j] = acc;
            m = fmaxf(m, acc);
        }
        float ssum = 0.f;
        for (int j = 0; j < E_; ++j) { g2[j] = expf(g2[j]-m); ssum += g2[j]; }
        for (int j = 0; j < E_; ++j) sg[j] = g2[j] / ssum;
    }
    __syncthreads();
    if (tid < K_) s[tid] = sg[tid / KG_] * Vsum[tid] * (1.0f/N_);
}

// ---------------------------------------------------------------------------
// P[ks] = partial of T = U^T X via MFMA.  v2: one-shot X stage (ONE barrier),
// U streamed global->register (A-frag col reads are lane-coalesced 128B),
// no barriers in K-loop.
// grid: (16 ctiles of 32 cols, 16 ksplits of 512 rows, 2 mhalf) = 512 blocks.
// Wave w owns mtile mt = 4*mhalf + w (U k-rows 32mt..32mt+31; mt>=7 garbage,
// discarded by the mm<200 epilogue guard; loads clamped in-bounds).
// Frag conv (verified): reg r <-> k-rows k0+2r,k0+2r+1, k0 = 16t+8hi.
// C/D: col = lane&31, row = mt*32 + (r&3)+8*(r>>2)+4*hi.
// ---------------------------------------------------------------------------
__global__ __launch_bounds__(256) void k_utx(
    const float* __restrict__ U, const float* __restrict__ X,
    float* __restrict__ P)
{
    const int c0    = blockIdx.x * 32;
    const int ks    = blockIdx.y;
    const int r0    = ks * 512;
    const int mhalf = blockIdx.z;
    const int tid = threadIdx.x;
    const int w   = tid >> 6;
    const int l   = tid & 63;
    const int lo  = l & 31;
    const int hi  = l >> 5;

    __shared__ uint spkX[256][32];   // 32 KB: pairs of X rows (r0+2rp, r0+2rp+1)

    // one-shot X stage: 2048 units (256 rp x 8 c4)
    for (int j = tid; j < 2048; j += 256) {
        const int rp = j >> 3, c4 = j & 7;
        const float4 a = *reinterpret_cast<const float4*>(&X[(r0+2*rp  )*CIN_ + c0 + 4*c4]);
        const float4 b = *reinterpret_cast<const float4*>(&X[(r0+2*rp+1)*CIN_ + c0 + 4*c4]);
        uint4 pk;
        pk.x = packbf(a.x, b.x); pk.y = packbf(a.y, b.y);
        pk.z = packbf(a.z, b.z); pk.w = packbf(a.w, b.w);
        *reinterpret_cast<uint4*>(&spkX[rp][4*c4]) = pk;
    }
    __syncthreads();

    const int mt   = mhalf*4 + w;
    const int colc = min(32*mt + lo, K_ - 1);   // clamp: garbage rows discarded

    f32x16 acc = {0};
    #pragma unroll 2
    for (int it = 0; it < 16; ++it) {
        const int rb = r0 + 32*it;
        #pragma unroll
        for (int t = 0; t < 2; ++t) {
            const int kr = rb + 16*t + 8*hi;
            union { uint u[4]; bf16x8 v; } ax;
            #pragma unroll
            for (int j2 = 0; j2 < 4; ++j2) {
                const float f0 = U[(kr + 2*j2    )*K_ + colc];
                const float f1 = U[(kr + 2*j2 + 1)*K_ + colc];
                ax.u[j2] = packbf(f0, f1);
            }
            UB bx;
            const int rpb = 16*it + 8*t + 4*hi;
            bx.q.x = spkX[rpb+0][lo];
            bx.q.y = spkX[rpb+1][lo];
            bx.q.z = spkX[rpb+2][lo];
            bx.q.w = spkX[rpb+3][lo];
            acc = __builtin_amdgcn_mfma_f32_32x32x16_bf16(ax.v, bx.v, acc, 0, 0, 0);
        }
    }

    #pragma unroll
    for (int r = 0; r < 16; ++r) {
        const int mm = 32*mt + (r & 3) + 8*(r >> 2) + 4*hi;
        if (mm < K_)
            P[(ks*K_ + mm)*CIN_ + c0 + lo] = acc[r];
    }
}

// ---------------------------------------------------------------------------
// T = sum_ks P[ks]   (200x512)
// ---------------------------------------------------------------------------
__global__ __launch_bounds__(256) void k_red(
    const float* __restrict__ P, float* __restrict__ T)
{
    const int j = blockIdx.x*256 + threadIdx.x;   // f4 index < 25600
    float4 s = {0.f, 0.f, 0.f, 0.f};
    for (int ks = 0; ks < KSPLIT_; ++ks) {
        const float4 v = *reinterpret_cast<const float4*>(&P[ks*K_*CIN_ + j*4]);
        s.x += v.x; s.y += v.y; s.z += v.z; s.w += v.w;
    }
    *reinterpret_cast<float4*>(&T[j*4]) = s;
}

// ---------------------------------------------------------------------------
// G = T @ Ww   [200][256]; grid 50 blocks of 4 k-rows; thread = output col.
// ---------------------------------------------------------------------------
__global__ __launch_bounds__(256) void k_g(
    const float* __restrict__ T, const float* __restrict__ Ww,
    float* __restrict__ G)
{
    const int k0  = blockIdx.x * 4;
    const int c   = threadIdx.x;
    __shared__ float4 sT4[4][128];

    for (int j = threadIdx.x; j < 512; j += 256) {
        const int r = j >> 7, c4 = j & 127;
        sT4[r][c4] = reinterpret_cast<const float4*>(T)[(k0+r)*128 + c4];
    }
    __syncthreads();

    float a0 = 0.f, a1 = 0.f, a2 = 0.f, a3 = 0.f;
    for (int ci4 = 0; ci4 < 128; ++ci4) {
        const float w0 = Ww[(4*ci4+0)*HID_ + c];
        const float w1 = Ww[(4*ci4+1)*HID_ + c];
        const float w2 = Ww[(4*ci4+2)*HID_ + c];
        const float w3 = Ww[(4*ci4+3)*HID_ + c];
        float4 t;
        t = sT4[0][ci4]; a0 += t.x*w0 + t.y*w1 + t.z*w2 + t.w*w3;
        t = sT4[1][ci4]; a1 += t.x*w0 + t.y*w1 + t.z*w2 + t.w*w3;
        t = sT4[2][ci4]; a2 += t.x*w0 + t.y*w1 + t.z*w2 + t.w*w3;
        t = sT4[3][ci4]; a3 += t.x*w0 + t.y*w1 + t.z*w2 + t.w*w3;
    }
    G[(k0+0)*HID_ + c] = a0;
    G[(k0+1)*HID_ + c] = a1;
    G[(k0+2)*HID_ + c] = a2;
    G[(k0+3)*HID_ + c] = a3;
}

// ---------------------------------------------------------------------------
// hidden = (U*s) @ G + Wb   [8192][256]  via MFMA (bf16 in, fp32 acc).
// grid: (4 col-tiles of 64, 64 row-tiles of 128) = 256 blocks; 4 waves.
// One-shot stage: spkA[104 kp][128 m] = (U*s) pairs (k 200 zero-pad to 208);
//                 spkB[104 kp][64 c]  = G pairs.  13 K-steps, 26 MFMA/wave.
// Wave w: rows 32w..32w+31; nt=0,1 cols.  Same frag/C-D conventions.
// ---------------------------------------------------------------------------
__global__ __launch_bounds__(256) void k_hidden(
    const float* __restrict__ U, const float* __restrict__ s,
    const float* __restrict__ G, const float* __restrict__ Wb,
    float* __restrict__ hid)
{
    const int c0  = blockIdx.x * 64;
    const int n0  = blockIdx.y * 128;
    const int tid = threadIdx.x;
    const int w   = tid >> 6;
    const int l   = tid & 63;
    const int lo  = l & 31;
    const int hi  = l >> 5;

    __shared__ uint  spkA[104][128];   // 53.2 KB
    __shared__ uint  spkB[104][64];    // 26.6 KB
    __shared__ float ss[K_];

    if (tid < K_) ss[tid] = s[tid];
    __syncthreads();

    // stage A = (U*s) rows n0..n0+127: units (m, g) g of 8 k
    for (int j = tid; j < 128*26; j += 256) {
        const int m = j & 127, g = j >> 7;
        uint4 pk = make_uint4(0u, 0u, 0u, 0u);
        if (g < 25) {
            const float4 a = *reinterpret_cast<const float4*>(&U[(n0+m)*K_ + 8*g]);
            const float4 b = *reinterpret_cast<const float4*>(&U[(n0+m)*K_ + 8*g + 4]);
            pk.x = packbf(a.x*ss[8*g+0], a.y*ss[8*g+1]);
            pk.y = packbf(a.z*ss[8*g+2], a.w*ss[8*g+3]);
            pk.z = packbf(b.x*ss[8*g+4], b.y*ss[8*g+5]);
            pk.w = packbf(b.z*ss[8*g+6], b.w*ss[8*g+7]);
        }
        spkA[4*g+0][m] = pk.x;
        spkA[4*g+1][m] = pk.y;
        spkA[4*g+2][m] = pk.z;
        spkA[4*g+3][m] = pk.w;
    }
    // stage B = G cols c0..c0+63
    for (int j = tid; j < 64*26; j += 256) {
        const int c = j & 63, g = j >> 6;
        uint4 pk = make_uint4(0u, 0u, 0u, 0u);
        if (g < 25) {
            const float v0 = G[(8*g+0)*HID_ + c0+c], v1 = G[(8*g+1)*HID_ + c0+c];
            const float v2 = G[(8*g+2)*HID_ + c0+c], v3 = G[(8*g+3)*HID_ + c0+c];
            const float v4 = G[(8*g+4)*HID_ + c0+c], v5 = G[(8*g+5)*HID_ + c0+c];
            const float v6 = G[(8*g+6)*HID_ + c0+c], v7 = G[(8*g+7)*HID_ + c0+c];
            pk.x = packbf(v0, v1); pk.y = packbf(v2, v3);
            pk.z = packbf(v4, v5); pk.w = packbf(v6, v7);
        }
        spkB[4*g+0][c] = pk.x;
        spkB[4*g+1][c] = pk.y;
        spkB[4*g+2][c] = pk.z;
        spkB[4*g+3][c] = pk.w;
    }
    __syncthreads();

    f32x16 acc0 = {0}, acc1 = {0};
    #pragma unroll
    for (int t = 0; t < 13; ++t) {
        const int kp = 8*t + 4*hi;
        union { uint u[4]; bf16x8 v; } fa;
        fa.u[0] = spkA[kp+0][32*w + lo];
        fa.u[1] = spkA[kp+1][32*w + lo];
        fa.u[2] = spkA[kp+2][32*w + lo];
        fa.u[3] = spkA[kp+3][32*w + lo];
        UB b0, b1;
        b0.q.x = spkB[kp+0][lo];      b0.q.y = spkB[kp+1][lo];
        b0.q.z = spkB[kp+2][lo];      b0.q.w = spkB[kp+3][lo];
        b1.q.x = spkB[kp+0][32 + lo]; b1.q.y = spkB[kp+1][32 + lo];
        b1.q.z = spkB[kp+2][32 + lo]; b1.q.w = spkB[kp+3][32 + lo];
        acc0 = __builtin_amdgcn_mfma_f32_32x32x16_bf16(fa.v, b0.v, acc0, 0, 0, 0);
        acc1 = __builtin_amdgcn_mfma_f32_32x32x16_bf16(fa.v, b1.v, acc1, 0, 0, 0);
    }

    const float wb0 = Wb[c0 + lo], wb1 = Wb[c0 + 32 + lo];
    #pragma unroll
    for (int r = 0; r < 16; ++r) {
        const int row = 32*w + (r & 3) + 8*(r >> 2) + 4*hi;
        hid[(n0+row)*HID_ + c0 + lo]      = acc0[r] + wb0;
        hid[(n0+row)*HID_ + c0 + 32 + lo] = acc1[r] + wb1;
    }
}

// ---------------------------------------------------------------------------
// BN batch stats (grid 256 x 32 rows)
// ---------------------------------------------------------------------------
__global__ __launch_bounds__(256) void k_bnstat(
    const float* __restrict__ hid, float* __restrict__ bnsum)
{
    const int c  = threadIdx.x;
    const int n0 = blockIdx.x * 32;
    float sm = 0.f, sq = 0.f;
    for (int r = 0; r < 32; ++r) {
        const float v = hid[(n0+r)*HID_ + c];
        sm += v; sq += v*v;
    }
    atomicAdd(&bnsum[c], sm);
    atomicAdd(&bnsum[HID_ + c], sq);
}

// ---------------------------------------------------------------------------
// logits = relu(BN(hidden)) @ Mw + Mb; out = log_softmax.
// grid 256; block 256 = 32 rows x 8 col-slices of 32; LDS combine (pad 41).
// ---------------------------------------------------------------------------
__global__ __launch_bounds__(256) void k_logits(
    const float* __restrict__ hid, const float* __restrict__ bnsum,
    const float* __restrict__ gamma, const float* __restrict__ beta,
    const float* __restrict__ Mw, const float* __restrict__ Mb,
    float* __restrict__ outls)
{
    __shared__ float sc[HID_], sh[HID_], sMb[COUT_];
    __shared__ float sMw[HID_][COUT_];        // 40 KB
    __shared__ float sPart[8][32][41];        // 42 KB (pad 41: conflict-free)

    const int tid = threadIdx.x;
    const int r   = tid & 31;
    const int sl  = tid >> 5;

    {
        const float sm = bnsum[tid], sq = bnsum[HID_+tid];
        const float mu  = sm * (1.0f/N_);
        const float var = sq * (1.0f/N_) - mu*mu;
        const float a   = gamma[tid] * rsqrtf(var + EPS_);
        sc[tid] = a;
        sh[tid] = beta[tid] - mu*a;
    }
    for (int j = tid; j < HID_*COUT_/4; j += 256)
        reinterpret_cast<float4*>(&sMw[0][0])[j] = reinterpret_cast<const float4*>(Mw)[j];
    if (tid < COUT_) sMb[tid] = Mb[tid];
    __syncthreads();

    const int n  = blockIdx.x*32 + r;
    const int cb = sl * 32;
    float acc[COUT_];
    #pragma unroll
    for (int j = 0; j < COUT_; ++j) acc[j] = 0.f;

    const float4* hrow = reinterpret_cast<const float4*>(&hid[n*HID_ + cb]);
    #pragma unroll
    for (int c4 = 0; c4 < 8; ++c4) {
        const float4 h4 = hrow[c4];
        const float hv[4] = {h4.x, h4.y, h4.z, h4.w};
        #pragma unroll
        for (int q = 0; q < 4; ++q) {
            const int c = cb + 4*c4 + q;
            const float hn = fmaxf(hv[q]*sc[c] + sh[c], 0.f);
            #pragma unroll
            for (int j0 = 0; j0 < COUT_; j0 += 4) {
                const float4 wv = *reinterpret_cast<const float4*>(&sMw[c][j0]);
                acc[j0+0] += hn*wv.x; acc[j0+1] += hn*wv.y;
                acc[j0+2] += hn*wv.z; acc[j0+3] += hn*wv.w;
            }
        }
    }
    #pragma unroll
    for (int j = 0; j < COUT_; ++j) sPart[sl][r][j] = acc[j];
    __syncthreads();

    if (tid < 32) {
        const int n2 = blockIdx.x*32 + tid;
        float a2[COUT_];
        #pragma unroll
        for (int j = 0; j < COUT_; ++j) {
            float sum = sMb[j];
            #pragma unroll
            for (int s2 = 0; s2 < 8; ++s2) sum += sPart[s2][tid][j];
            a2[j] = sum;
        }
        float m = -1e30f;
        #pragma unroll
        for (int j = 0; j < COUT_; ++j) m = fmaxf(m, a2[j]);
        float ssum = 0.f;
        #pragma unroll
        for (int j = 0; j < COUT_; ++j) ssum += expf(a2[j] - m);
        const float lse = m + logf(ssum);
        #pragma unroll
        for (int j = 0; j < COUT_; ++j)
            outls[n2*COUT_ + j] = a2[j] - lse;
    }
}

// ---------------------------------------------------------------------------
extern "C" void kernel_launch(void* const* d_in, const int* in_sizes, int n_in,
                              void* d_out, int out_size, void* d_ws, size_t ws_size,
                              hipStream_t stream)
{
    const float* X        = (const float*)d_in[0];
    const float* La       = (const float*)d_in[1];
    const float* U        = (const float*)d_in[2];
    const float* eW1      = (const float*)d_in[3];
    const float* eb1      = (const float*)d_in[4];
    const float* eW2      = (const float*)d_in[5];
    const float* eb2      = (const float*)d_in[6];
    const float* eW3      = (const float*)d_in[7];
    const float* eb3      = (const float*)d_in[8];
    const float* gW1      = (const float*)d_in[9];
    const float* gb1      = (const float*)d_in[10];
    const float* gW2      = (const float*)d_in[11];
    const float* gb2      = (const float*)d_in[12];
    const float* Ww       = (const float*)d_in[13];
    const float* Wb       = (const float*)d_in[14];
    const float* bn_gamma = (const float*)d_in[15];
    const float* bn_beta  = (const float*)d_in[16];
    const float* Mw       = (const float*)d_in[17];
    const float* Mb       = (const float*)d_in[18];

    float* out   = (float*)d_out;
    float* ws    = (float*)d_ws;
    float* Vsum  = ws + WS_VSUM;
    float* bnsum = ws + WS_BNSUM;
    float* T     = ws + WS_T;
    float* s     = ws + WS_S;
    float* G     = ws + WS_G;

    float* outls = out;                 // [8192][40] log_softmax (written LAST)
    float* hid   = out + N_*COUT_;      // [8192][256] hidden (output 1)
    float* P     = out;                 // d_out reused as k_utx partial scratch
                                        // (6.55 MB < 9.7 MB), consumed by k_red
                                        // before k_hidden overwrites.

    // zero Vsum + bnsum (atomic accumulators)
    hipMemsetAsync(ws, 0, (size_t)768 * sizeof(float), stream);

    k_utx   <<<dim3(16, KSPLIT_, 2), 256, 0, stream>>>(U, X, P);
    k_expert<<<dim3(E_, 320),        256, 0, stream>>>(U, eW1, eb1, eW2, eb2, eW3, eb3, Vsum);
    k_gate  <<<1,   256, 0, stream>>>(La, gW1, gb1, gW2, gb2, Vsum, s);
    k_red   <<<100, 256, 0, stream>>>(P, T);
    k_g     <<<50,  256, 0, stream>>>(T, Ww, G);
    k_hidden<<<dim3(4, 64), 256, 0, stream>>>(U, s, G, Wb, hid);
    k_bnstat<<<256, 256, 0, stream>>>(hid, bnsum);
    k_logits<<<256, 256, 0, stream>>>(hid, bnsum, bn_gamma, bn_beta, Mw, Mb, outls);
}

// Round 5
// 235.820 us; speedup vs baseline: 4.4758x; 1.0392x over previous
//
#include <hip/hip_runtime.h>
#include <hip/hip_bf16.h>

// Problem constants
#define N_    8192
#define K_    200
#define CIN_  512
#define HID_  256
#define COUT_ 40
#define E_    5
#define MH_   64
#define KG_   40
#define EPS_  1e-5f

// Workspace layout (floats):
#define WS_VSUM  0
#define WS_BNSUM 256
#define WS_T     768
#define WS_S     103168
#define WS_G     103424

typedef __bf16 bf16x8 __attribute__((ext_vector_type(8)));
typedef float  f32x16 __attribute__((ext_vector_type(16)));

__device__ __forceinline__ uint packbf(float a, float b) {
    union { __bf16 h[2]; uint u; } p;
    p.h[0] = (__bf16)a; p.h[1] = (__bf16)b;
    return p.u;
}

union UB { uint4 q; bf16x8 v; };

// ---------------------------------------------------------------------------
// Expert MLP via MFMA.  v3: B-fragments built entirely in-register.
// B-frag identity: reg r of k-step t holds h1[col][16t+8hi+2r, +1] with
// col = 32nt+lo -> ucol = shfl(u, 32nt+lo); h1 = relu(ucol*W1[k]+b1[k]).
// Same fp32 math as the (verified) LDS path -> bit-identical results.
// A (W2^T) frags + C/D epilogue unchanged (verified rounds 2-4).
// ---------------------------------------------------------------------------
__global__ __launch_bounds__(256) void k_expert(
    const float* __restrict__ U,
    const float* __restrict__ eW1, const float* __restrict__ eb1,
    const float* __restrict__ eW2, const float* __restrict__ eb2,
    const float* __restrict__ eW3, const float* __restrict__ eb3,
    float* __restrict__ Vsum)
{
    const int e   = blockIdx.x;
    const int tid = threadIdx.x;
    const int w   = tid >> 6;        // wave 0..3
    const int l   = tid & 63;        // lane
    const int lo  = l & 31;
    const int hi  = l >> 5;

    __shared__ float sW1[MH_], sb1[MH_], sb2s[MH_], sW3s[MH_];
    __shared__ float colsum[KG_];

    if (tid < MH_) {
        sW1[tid]  = eW1[e*MH_ + tid];
        sb1[tid]  = eb1[e*MH_ + tid];
        sb2s[tid] = eb2[e*MH_ + tid];
        sW3s[tid] = eW3[e*MH_ + tid];
    }
    if (tid < KG_) colsum[tid] = 0.f;
    const float b3 = eb3[e];

    // A fragments (W2^T), 8 frags x 4 VGPRs.
    bf16x8 fa[2][4];
    {
        const float* W2e = eW2 + e*MH_*MH_;
        #pragma unroll
        for (int mt = 0; mt < 2; ++mt) {
            const int grow = mt*32 + lo;
            #pragma unroll
            for (int t = 0; t < 4; ++t) {
                const int k0 = 16*t + 8*hi;
                union { uint u[4]; bf16x8 v; } fb;
                #pragma unroll
                for (int r = 0; r < 4; ++r) {
                    const float x0 = W2e[(k0+2*r  )*MH_ + grow];
                    const float x1 = W2e[(k0+2*r+1)*MH_ + grow];
                    fb.u[r] = packbf(x0, x1);
                }
                fa[mt][t] = fb.v;
            }
        }
    }
    __syncthreads();

    for (int it = 0; it < 4; ++it) {
        const int tile  = (blockIdx.y*16 + it*4 + w);
        const int elem0 = tile * 64;
        const int idx   = elem0 + l;
        const int n     = idx / KG_;
        const int kg    = idx - n*KG_;
        const float u   = U[n*K_ + e*KG_ + kg];

        const float ucol0 = __shfl(u, lo);        // u of elem col lo
        const float ucol1 = __shfl(u, 32 + lo);   // u of elem col 32+lo

        f32x16 acc00 = {0}; f32x16 acc10 = {0};
        f32x16 acc01 = {0}; f32x16 acc11 = {0};
        #pragma unroll
        for (int t = 0; t < 4; ++t) {
            const int k0 = 16*t + 8*hi;
            float2 w1p[4], b1p[4];
            #pragma unroll
            for (int r = 0; r < 4; ++r) {
                w1p[r] = *reinterpret_cast<const float2*>(&sW1[k0 + 2*r]);
                b1p[r] = *reinterpret_cast<const float2*>(&sb1[k0 + 2*r]);
            }
            union { uint u[4]; bf16x8 v; } b0, b1;
            #pragma unroll
            for (int r = 0; r < 4; ++r) {
                const float pa = fmaxf(fmaf(ucol0, w1p[r].x, b1p[r].x), 0.f);
                const float pb = fmaxf(fmaf(ucol0, w1p[r].y, b1p[r].y), 0.f);
                b0.u[r] = packbf(pa, pb);
                const float qa = fmaxf(fmaf(ucol1, w1p[r].x, b1p[r].x), 0.f);
                const float qb = fmaxf(fmaf(ucol1, w1p[r].y, b1p[r].y), 0.f);
                b1.u[r] = packbf(qa, qb);
            }
            acc00 = __builtin_amdgcn_mfma_f32_32x32x16_bf16(fa[0][t], b0.v, acc00, 0, 0, 0);
            acc10 = __builtin_amdgcn_mfma_f32_32x32x16_bf16(fa[1][t], b0.v, acc10, 0, 0, 0);
            acc01 = __builtin_amdgcn_mfma_f32_32x32x16_bf16(fa[0][t], b1.v, acc01, 0, 0, 0);
            acc11 = __builtin_amdgcn_mfma_f32_32x32x16_bf16(fa[1][t], b1.v, acc11, 0, 0, 0);
        }

        // epilogue: v = sum_g relu(D+b2[g])*W3[g], join row-halves, + b3
        float vs0 = 0.f, vs1 = 0.f;
        #pragma unroll
        for (int r = 0; r < 16; ++r) {
            const int gb  = (r & 3) + 8*(r >> 2) + 4*hi;
            const float b2a = sb2s[gb],      w3a = sW3s[gb];
            const float b2b = sb2s[32 + gb], w3b = sW3s[32 + gb];
            vs0 += fmaxf(acc00[r] + b2a, 0.f)*w3a + fmaxf(acc10[r] + b2b, 0.f)*w3b;
            vs1 += fmaxf(acc01[r] + b2a, 0.f)*w3a + fmaxf(acc11[r] + b2b, 0.f)*w3b;
        }
        vs0 += __shfl_xor(vs0, 32);
        vs1 += __shfl_xor(vs1, 32);

        const float myv    = (hi ? vs1 : vs0) + b3;
        const int   myelem = (hi ? 32 : 0) + lo;
        const int   mykg   = (elem0 + myelem) % KG_;
        atomicAdd(&colsum[mykg], myv);
    }

    __syncthreads();
    if (tid < KG_) atomicAdd(&Vsum[e*KG_ + tid], colsum[tid]);
}

// ---------------------------------------------------------------------------
// Gate (unchanged)
// ---------------------------------------------------------------------------
__global__ void k_gate(
    const float* __restrict__ La,
    const float* __restrict__ gW1, const float* __restrict__ gb1,
    const float* __restrict__ gW2, const float* __restrict__ gb2,
    const float* __restrict__ Vsum, float* __restrict__ s)
{
    __shared__ float sg[E_];
    const int tid = threadIdx.x;
    if (tid == 0) {
        float stats[E_], g1[E_], g2[E_];
        for (int e = 0; e < E_; ++e) {
            float acc = 0.f;
            for (int k = 0; k < KG_; ++k) acc += La[e*KG_ + k];
            stats[e] = acc * (1.0f/KG_);
        }
        for (int j = 0; j < E_; ++j) {
            float acc = gb1[j];
            for (int i = 0; i < E_; ++i) acc += stats[i]*gW1[i*E_ + j];
            g1[j] = fmaxf(acc, 0.f);
        }
        float m = -1e30f;
        for (int j = 0; j < E_; ++j) {
            float acc = gb2[j];
            for (int i = 0; i < E_; ++i) acc += g1[i]*gW2[i*E_ + j];
            g2[j] = acc;
            m = fmaxf(m, acc);
        }
        float ssum = 0.f;
        for (int j = 0; j < E_; ++j) { g2[j] = expf(g2[j]-m); ssum += g2[j]; }
        for (int j = 0; j < E_; ++j) sg[j] = g2[j] / ssum;
    }
    __syncthreads();
    if (tid < K_) s[tid] = sg[tid / KG_] * Vsum[tid] * (1.0f/N_);
}

// ---------------------------------------------------------------------------
// T += U^T X partials via MFMA.  v3: NO LDS, both operands streamed
// global->register (all reads lane-coalesced 128B segments), 32 waves/CU,
// fp32 atomicAdd epilogue straight into T (k_red removed).
// grid: (16 ctiles of 32 cols, 64 ksplits of 128 rows, 2 mhalf) = 2048 blocks.
// Wave w: mt = 4*mhalf + w (mt=7 garbage, guarded off in epilogue).
// Frag conv (verified): reg r <-> k-rows kr+2r, kr+2r+1, kr = 16s+8hi.
// C/D: col = lane&31, row = mt*32 + (r&3)+8*(r>>2)+4*hi.
// ---------------------------------------------------------------------------
__global__ __launch_bounds__(256) void k_utx(
    const float* __restrict__ U, const float* __restrict__ X,
    float* __restrict__ T)
{
    const int c0    = blockIdx.x * 32;
    const int r0    = blockIdx.y * 128;
    const int mhalf = blockIdx.z;
    const int tid = threadIdx.x;
    const int w   = tid >> 6;
    const int l   = tid & 63;
    const int lo  = l & 31;
    const int hi  = l >> 5;

    const int mt   = mhalf*4 + w;
    const int colc = min(32*mt + lo, K_ - 1);   // clamp: garbage discarded
    const int xcol = c0 + lo;

    f32x16 acc = {0};
    #pragma unroll
    for (int s = 0; s < 8; ++s) {
        const int kr = r0 + 16*s + 8*hi;
        union { uint u[4]; bf16x8 v; } ax, bx;
        #pragma unroll
        for (int j2 = 0; j2 < 4; ++j2) {
            const float ua = U[(kr + 2*j2    )*K_ + colc];
            const float ub = U[(kr + 2*j2 + 1)*K_ + colc];
            ax.u[j2] = packbf(ua, ub);
            const float xa = X[(kr + 2*j2    )*CIN_ + xcol];
            const float xb = X[(kr + 2*j2 + 1)*CIN_ + xcol];
            bx.u[j2] = packbf(xa, xb);
        }
        acc = __builtin_amdgcn_mfma_f32_32x32x16_bf16(ax.v, bx.v, acc, 0, 0, 0);
    }

    #pragma unroll
    for (int r = 0; r < 16; ++r) {
        const int mm = 32*mt + (r & 3) + 8*(r >> 2) + 4*hi;
        if (mm < K_)
            atomicAdd(&T[mm*CIN_ + c0 + lo], acc[r]);
    }
}

// ---------------------------------------------------------------------------
// G = T @ Ww   [200][256]; grid 50 blocks of 4 k-rows; thread = output col.
// ---------------------------------------------------------------------------
__global__ __launch_bounds__(256) void k_g(
    const float* __restrict__ T, const float* __restrict__ Ww,
    float* __restrict__ G)
{
    const int k0  = blockIdx.x * 4;
    const int c   = threadIdx.x;
    __shared__ float4 sT4[4][128];

    for (int j = threadIdx.x; j < 512; j += 256) {
        const int r = j >> 7, c4 = j & 127;
        sT4[r][c4] = reinterpret_cast<const float4*>(T)[(k0+r)*128 + c4];
    }
    __syncthreads();

    float a0 = 0.f, a1 = 0.f, a2 = 0.f, a3 = 0.f;
    for (int ci4 = 0; ci4 < 128; ++ci4) {
        const float w0 = Ww[(4*ci4+0)*HID_ + c];
        const float w1 = Ww[(4*ci4+1)*HID_ + c];
        const float w2 = Ww[(4*ci4+2)*HID_ + c];
        const float w3 = Ww[(4*ci4+3)*HID_ + c];
        float4 t;
        t = sT4[0][ci4]; a0 += t.x*w0 + t.y*w1 + t.z*w2 + t.w*w3;
        t = sT4[1][ci4]; a1 += t.x*w0 + t.y*w1 + t.z*w2 + t.w*w3;
        t = sT4[2][ci4]; a2 += t.x*w0 + t.y*w1 + t.z*w2 + t.w*w3;
        t = sT4[3][ci4]; a3 += t.x*w0 + t.y*w1 + t.z*w2 + t.w*w3;
    }
    G[(k0+0)*HID_ + c] = a0;
    G[(k0+1)*HID_ + c] = a1;
    G[(k0+2)*HID_ + c] = a2;
    G[(k0+3)*HID_ + c] = a3;
}

// ---------------------------------------------------------------------------
// hidden = (U*s) @ G + Wb   [8192][256]  via MFMA (unchanged from round 4).
// ---------------------------------------------------------------------------
__global__ __launch_bounds__(256) void k_hidden(
    const float* __restrict__ U, const float* __restrict__ s,
    const float* __restrict__ G, const float* __restrict__ Wb,
    float* __restrict__ hid)
{
    const int c0  = blockIdx.x * 64;
    const int n0  = blockIdx.y * 128;
    const int tid = threadIdx.x;
    const int w   = tid >> 6;
    const int l   = tid & 63;
    const int lo  = l & 31;
    const int hi  = l >> 5;

    __shared__ uint  spkA[104][128];   // 53.2 KB
    __shared__ uint  spkB[104][64];    // 26.6 KB
    __shared__ float ss[K_];

    if (tid < K_) ss[tid] = s[tid];
    __syncthreads();

    for (int j = tid; j < 128*26; j += 256) {
        const int m = j & 127, g = j >> 7;
        uint4 pk = make_uint4(0u, 0u, 0u, 0u);
        if (g < 25) {
            const float4 a = *reinterpret_cast<const float4*>(&U[(n0+m)*K_ + 8*g]);
            const float4 b = *reinterpret_cast<const float4*>(&U[(n0+m)*K_ + 8*g + 4]);
            pk.x = packbf(a.x*ss[8*g+0], a.y*ss[8*g+1]);
            pk.y = packbf(a.z*ss[8*g+2], a.w*ss[8*g+3]);
            pk.z = packbf(b.x*ss[8*g+4], b.y*ss[8*g+5]);
            pk.w = packbf(b.z*ss[8*g+6], b.w*ss[8*g+7]);
        }
        spkA[4*g+0][m] = pk.x;
        spkA[4*g+1][m] = pk.y;
        spkA[4*g+2][m] = pk.z;
        spkA[4*g+3][m] = pk.w;
    }
    for (int j = tid; j < 64*26; j += 256) {
        const int c = j & 63, g = j >> 6;
        uint4 pk = make_uint4(0u, 0u, 0u, 0u);
        if (g < 25) {
            const float v0 = G[(8*g+0)*HID_ + c0+c], v1 = G[(8*g+1)*HID_ + c0+c];
            const float v2 = G[(8*g+2)*HID_ + c0+c], v3 = G[(8*g+3)*HID_ + c0+c];
            const float v4 = G[(8*g+4)*HID_ + c0+c], v5 = G[(8*g+5)*HID_ + c0+c];
            const float v6 = G[(8*g+6)*HID_ + c0+c], v7 = G[(8*g+7)*HID_ + c0+c];
            pk.x = packbf(v0, v1); pk.y = packbf(v2, v3);
            pk.z = packbf(v4, v5); pk.w = packbf(v6, v7);
        }
        spkB[4*g+0][c] = pk.x;
        spkB[4*g+1][c] = pk.y;
        spkB[4*g+2][c] = pk.z;
        spkB[4*g+3][c] = pk.w;
    }
    __syncthreads();

    f32x16 acc0 = {0}, acc1 = {0};
    #pragma unroll
    for (int t = 0; t < 13; ++t) {
        const int kp = 8*t + 4*hi;
        union { uint u[4]; bf16x8 v; } fa;
        fa.u[0] = spkA[kp+0][32*w + lo];
        fa.u[1] = spkA[kp+1][32*w + lo];
        fa.u[2] = spkA[kp+2][32*w + lo];
        fa.u[3] = spkA[kp+3][32*w + lo];
        UB b0, b1;
        b0.q.x = spkB[kp+0][lo];      b0.q.y = spkB[kp+1][lo];
        b0.q.z = spkB[kp+2][lo];      b0.q.w = spkB[kp+3][lo];
        b1.q.x = spkB[kp+0][32 + lo]; b1.q.y = spkB[kp+1][32 + lo];
        b1.q.z = spkB[kp+2][32 + lo]; b1.q.w = spkB[kp+3][32 + lo];
        acc0 = __builtin_amdgcn_mfma_f32_32x32x16_bf16(fa.v, b0.v, acc0, 0, 0, 0);
        acc1 = __builtin_amdgcn_mfma_f32_32x32x16_bf16(fa.v, b1.v, acc1, 0, 0, 0);
    }

    const float wb0 = Wb[c0 + lo], wb1 = Wb[c0 + 32 + lo];
    #pragma unroll
    for (int r = 0; r < 16; ++r) {
        const int row = 32*w + (r & 3) + 8*(r >> 2) + 4*hi;
        hid[(n0+row)*HID_ + c0 + lo]      = acc0[r] + wb0;
        hid[(n0+row)*HID_ + c0 + 32 + lo] = acc1[r] + wb1;
    }
}

// ---------------------------------------------------------------------------
// BN batch stats (grid 256 x 32 rows)
// ---------------------------------------------------------------------------
__global__ __launch_bounds__(256) void k_bnstat(
    const float* __restrict__ hid, float* __restrict__ bnsum)
{
    const int c  = threadIdx.x;
    const int n0 = blockIdx.x * 32;
    float sm = 0.f, sq = 0.f;
    for (int r = 0; r < 32; ++r) {
        const float v = hid[(n0+r)*HID_ + c];
        sm += v; sq += v*v;
    }
    atomicAdd(&bnsum[c], sm);
    atomicAdd(&bnsum[HID_ + c], sq);
}

// ---------------------------------------------------------------------------
// logits = relu(BN(hidden)) @ Mw + Mb; out = log_softmax.
// grid 256; block 256 = 32 rows x 8 col-slices of 32; LDS combine (pad 41).
// ---------------------------------------------------------------------------
__global__ __launch_bounds__(256) void k_logits(
    const float* __restrict__ hid, const float* __restrict__ bnsum,
    const float* __restrict__ gamma, const float* __restrict__ beta,
    const float* __restrict__ Mw, const float* __restrict__ Mb,
    float* __restrict__ outls)
{
    __shared__ float sc[HID_], sh[HID_], sMb[COUT_];
    __shared__ float sMw[HID_][COUT_];        // 40 KB
    __shared__ float sPart[8][32][41];        // 42 KB (pad 41: conflict-free)

    const int tid = threadIdx.x;
    const int r   = tid & 31;
    const int sl  = tid >> 5;

    {
        const float sm = bnsum[tid], sq = bnsum[HID_+tid];
        const float mu  = sm * (1.0f/N_);
        const float var = sq * (1.0f/N_) - mu*mu;
        const float a   = gamma[tid] * rsqrtf(var + EPS_);
        sc[tid] = a;
        sh[tid] = beta[tid] - mu*a;
    }
    for (int j = tid; j < HID_*COUT_/4; j += 256)
        reinterpret_cast<float4*>(&sMw[0][0])[j] = reinterpret_cast<const float4*>(Mw)[j];
    if (tid < COUT_) sMb[tid] = Mb[tid];
    __syncthreads();

    const int n  = blockIdx.x*32 + r;
    const int cb = sl * 32;
    float acc[COUT_];
    #pragma unroll
    for (int j = 0; j < COUT_; ++j) acc[j] = 0.f;

    const float4* hrow = reinterpret_cast<const float4*>(&hid[n*HID_ + cb]);
    #pragma unroll
    for (int c4 = 0; c4 < 8; ++c4) {
        const float4 h4 = hrow[c4];
        const float hv[4] = {h4.x, h4.y, h4.z, h4.w};
        #pragma unroll
        for (int q = 0; q < 4; ++q) {
            const int c = cb + 4*c4 + q;
            const float hn = fmaxf(hv[q]*sc[c] + sh[c], 0.f);
            #pragma unroll
            for (int j0 = 0; j0 < COUT_; j0 += 4) {
                const float4 wv = *reinterpret_cast<const float4*>(&sMw[c][j0]);
                acc[j0+0] += hn*wv.x; acc[j0+1] += hn*wv.y;
                acc[j0+2] += hn*wv.z; acc[j0+3] += hn*wv.w;
            }
        }
    }
    #pragma unroll
    for (int j = 0; j < COUT_; ++j) sPart[sl][r][j] = acc[j];
    __syncthreads();

    if (tid < 32) {
        const int n2 = blockIdx.x*32 + tid;
        float a2[COUT_];
        #pragma unroll
        for (int j = 0; j < COUT_; ++j) {
            float sum = sMb[j];
            #pragma unroll
            for (int s2 = 0; s2 < 8; ++s2) sum += sPart[s2][tid][j];
            a2[j] = sum;
        }
        float m = -1e30f;
        #pragma unroll
        for (int j = 0; j < COUT_; ++j) m = fmaxf(m, a2[j]);
        float ssum = 0.f;
        #pragma unroll
        for (int j = 0; j < COUT_; ++j) ssum += expf(a2[j] - m);
        const float lse = m + logf(ssum);
        #pragma unroll
        for (int j = 0; j < COUT_; ++j)
            outls[n2*COUT_ + j] = a2[j] - lse;
    }
}

// ---------------------------------------------------------------------------
extern "C" void kernel_launch(void* const* d_in, const int* in_sizes, int n_in,
                              void* d_out, int out_size, void* d_ws, size_t ws_size,
                              hipStream_t stream)
{
    const float* X        = (const float*)d_in[0];
    const float* La       = (const float*)d_in[1];
    const float* U        = (const float*)d_in[2];
    const float* eW1      = (const float*)d_in[3];
    const float* eb1      = (const float*)d_in[4];
    const float* eW2      = (const float*)d_in[5];
    const float* eb2      = (const float*)d_in[6];
    const float* eW3      = (const float*)d_in[7];
    const float* eb3      = (const float*)d_in[8];
    const float* gW1      = (const float*)d_in[9];
    const float* gb1      = (const float*)d_in[10];
    const float* gW2      = (const float*)d_in[11];
    const float* gb2      = (const float*)d_in[12];
    const float* Ww       = (const float*)d_in[13];
    const float* Wb       = (const float*)d_in[14];
    const float* bn_gamma = (const float*)d_in[15];
    const float* bn_beta  = (const float*)d_in[16];
    const float* Mw       = (const float*)d_in[17];
    const float* Mb       = (const float*)d_in[18];

    float* out   = (float*)d_out;
    float* ws    = (float*)d_ws;
    float* Vsum  = ws + WS_VSUM;
    float* bnsum = ws + WS_BNSUM;
    float* T     = ws + WS_T;
    float* s     = ws + WS_S;
    float* G     = ws + WS_G;

    float* outls = out;                 // [8192][40] log_softmax
    float* hid   = out + N_*COUT_;      // [8192][256] hidden (output 1)

    // zero Vsum + bnsum + T (k_utx accumulates into T with atomics)
    hipMemsetAsync(ws, 0, (size_t)(WS_T + K_*CIN_) * sizeof(float), stream);

    k_utx   <<<dim3(16, 64, 2), 256, 0, stream>>>(U, X, T);
    k_expert<<<dim3(E_, 320),   256, 0, stream>>>(U, eW1, eb1, eW2, eb2, eW3, eb3, Vsum);
    k_gate  <<<1,   256, 0, stream>>>(La, gW1, gb1, gW2, gb2, Vsum, s);
    k_g     <<<50,  256, 0, stream>>>(T, Ww, G);
    k_hidden<<<dim3(4, 64), 256, 0, stream>>>(U, s, G, Wb, hid);
    k_bnstat<<<256, 256, 0, stream>>>(hid, bnsum);
    k_logits<<<256, 256, 0, stream>>>(hid, bnsum, bn_gamma, bn_beta, Mw, Mb, outls);
}

// Round 6
// 214.617 us; speedup vs baseline: 4.9180x; 1.0988x over previous
//
#include <hip/hip_runtime.h>
#include <hip/hip_bf16.h>

// Problem constants
#define N_    8192
#define K_    200
#define CIN_  512
#define HID_  256
#define COUT_ 40
#define E_    5
#define MH_   64
#define KG_   40
#define EPS_  1e-5f

// Workspace layout (floats):
#define WS_VSUM  0
#define WS_BNSUM 256
#define WS_T     768
#define WS_S     103168
#define WS_G     103424

typedef __bf16 bf16x8 __attribute__((ext_vector_type(8)));
typedef float  f32x16 __attribute__((ext_vector_type(16)));

__device__ __forceinline__ uint packbf(float a, float b) {
    union { __bf16 h[2]; uint u; } p;
    p.h[0] = (__bf16)a; p.h[1] = (__bf16)b;
    return p.u;
}

union UB { uint4 q; bf16x8 v; };

// ---------------------------------------------------------------------------
// Expert MLP via MFMA, B-fragments built in-register (verified round 5).
// ---------------------------------------------------------------------------
__global__ __launch_bounds__(256) void k_expert(
    const float* __restrict__ U,
    const float* __restrict__ eW1, const float* __restrict__ eb1,
    const float* __restrict__ eW2, const float* __restrict__ eb2,
    const float* __restrict__ eW3, const float* __restrict__ eb3,
    float* __restrict__ Vsum)
{
    const int e   = blockIdx.x;
    const int tid = threadIdx.x;
    const int w   = tid >> 6;        // wave 0..3
    const int l   = tid & 63;        // lane
    const int lo  = l & 31;
    const int hi  = l >> 5;

    __shared__ float sW1[MH_], sb1[MH_], sb2s[MH_], sW3s[MH_];
    __shared__ float colsum[KG_];

    if (tid < MH_) {
        sW1[tid]  = eW1[e*MH_ + tid];
        sb1[tid]  = eb1[e*MH_ + tid];
        sb2s[tid] = eb2[e*MH_ + tid];
        sW3s[tid] = eW3[e*MH_ + tid];
    }
    if (tid < KG_) colsum[tid] = 0.f;
    const float b3 = eb3[e];

    // A fragments (W2^T), 8 frags x 4 VGPRs.
    bf16x8 fa[2][4];
    {
        const float* W2e = eW2 + e*MH_*MH_;
        #pragma unroll
        for (int mt = 0; mt < 2; ++mt) {
            const int grow = mt*32 + lo;
            #pragma unroll
            for (int t = 0; t < 4; ++t) {
                const int k0 = 16*t + 8*hi;
                union { uint u[4]; bf16x8 v; } fb;
                #pragma unroll
                for (int r = 0; r < 4; ++r) {
                    const float x0 = W2e[(k0+2*r  )*MH_ + grow];
                    const float x1 = W2e[(k0+2*r+1)*MH_ + grow];
                    fb.u[r] = packbf(x0, x1);
                }
                fa[mt][t] = fb.v;
            }
        }
    }
    __syncthreads();

    for (int it = 0; it < 4; ++it) {
        const int tile  = (blockIdx.y*16 + it*4 + w);
        const int elem0 = tile * 64;
        const int idx   = elem0 + l;
        const int n     = idx / KG_;
        const int kg    = idx - n*KG_;
        const float u   = U[n*K_ + e*KG_ + kg];

        const float ucol0 = __shfl(u, lo);        // u of elem col lo
        const float ucol1 = __shfl(u, 32 + lo);   // u of elem col 32+lo

        f32x16 acc00 = {0}; f32x16 acc10 = {0};
        f32x16 acc01 = {0}; f32x16 acc11 = {0};
        #pragma unroll
        for (int t = 0; t < 4; ++t) {
            const int k0 = 16*t + 8*hi;
            float2 w1p[4], b1p[4];
            #pragma unroll
            for (int r = 0; r < 4; ++r) {
                w1p[r] = *reinterpret_cast<const float2*>(&sW1[k0 + 2*r]);
                b1p[r] = *reinterpret_cast<const float2*>(&sb1[k0 + 2*r]);
            }
            union { uint u[4]; bf16x8 v; } b0, b1;
            #pragma unroll
            for (int r = 0; r < 4; ++r) {
                const float pa = fmaxf(fmaf(ucol0, w1p[r].x, b1p[r].x), 0.f);
                const float pb = fmaxf(fmaf(ucol0, w1p[r].y, b1p[r].y), 0.f);
                b0.u[r] = packbf(pa, pb);
                const float qa = fmaxf(fmaf(ucol1, w1p[r].x, b1p[r].x), 0.f);
                const float qb = fmaxf(fmaf(ucol1, w1p[r].y, b1p[r].y), 0.f);
                b1.u[r] = packbf(qa, qb);
            }
            acc00 = __builtin_amdgcn_mfma_f32_32x32x16_bf16(fa[0][t], b0.v, acc00, 0, 0, 0);
            acc10 = __builtin_amdgcn_mfma_f32_32x32x16_bf16(fa[1][t], b0.v, acc10, 0, 0, 0);
            acc01 = __builtin_amdgcn_mfma_f32_32x32x16_bf16(fa[0][t], b1.v, acc01, 0, 0, 0);
            acc11 = __builtin_amdgcn_mfma_f32_32x32x16_bf16(fa[1][t], b1.v, acc11, 0, 0, 0);
        }

        float vs0 = 0.f, vs1 = 0.f;
        #pragma unroll
        for (int r = 0; r < 16; ++r) {
            const int gb  = (r & 3) + 8*(r >> 2) + 4*hi;
            const float b2a = sb2s[gb],      w3a = sW3s[gb];
            const float b2b = sb2s[32 + gb], w3b = sW3s[32 + gb];
            vs0 += fmaxf(acc00[r] + b2a, 0.f)*w3a + fmaxf(acc10[r] + b2b, 0.f)*w3b;
            vs1 += fmaxf(acc01[r] + b2a, 0.f)*w3a + fmaxf(acc11[r] + b2b, 0.f)*w3b;
        }
        vs0 += __shfl_xor(vs0, 32);
        vs1 += __shfl_xor(vs1, 32);

        const float myv    = (hi ? vs1 : vs0) + b3;
        const int   myelem = (hi ? 32 : 0) + lo;
        const int   mykg   = (elem0 + myelem) % KG_;
        atomicAdd(&colsum[mykg], myv);
    }

    __syncthreads();
    if (tid < KG_) atomicAdd(&Vsum[e*KG_ + tid], colsum[tid]);
}

// ---------------------------------------------------------------------------
// Gate (unchanged)
// ---------------------------------------------------------------------------
__global__ void k_gate(
    const float* __restrict__ La,
    const float* __restrict__ gW1, const float* __restrict__ gb1,
    const float* __restrict__ gW2, const float* __restrict__ gb2,
    const float* __restrict__ Vsum, float* __restrict__ s)
{
    __shared__ float sg[E_];
    const int tid = threadIdx.x;
    if (tid == 0) {
        float stats[E_], g1[E_], g2[E_];
        for (int e = 0; e < E_; ++e) {
            float acc = 0.f;
            for (int k = 0; k < KG_; ++k) acc += La[e*KG_ + k];
            stats[e] = acc * (1.0f/KG_);
        }
        for (int j = 0; j < E_; ++j) {
            float acc = gb1[j];
            for (int i = 0; i < E_; ++i) acc += stats[i]*gW1[i*E_ + j];
            g1[j] = fmaxf(acc, 0.f);
        }
        float m = -1e30f;
        for (int j = 0; j < E_; ++j) {
            float acc = gb2[j];
            for (int i = 0; i < E_; ++i) acc += g1[i]*gW2[i*E_ + j];
            g2[j] = acc;
            m = fmaxf(m, acc);
        }
        float ssum = 0.f;
        for (int j = 0; j < E_; ++j) { g2[j] = expf(g2[j]-m); ssum += g2[j]; }
        for (int j = 0; j < E_; ++j) sg[j] = g2[j] / ssum;
    }
    __syncthreads();
    if (tid < K_) s[tid] = sg[tid / KG_] * Vsum[tid] * (1.0f/N_);
}

// ---------------------------------------------------------------------------
// T += U^T X partials via MFMA.  v4: merged mtiles (X read ONCE), explicit
// 2-deep software-pipelined loads (named register buffers, static indices)
// so ~24 loads stay in flight across each MFMA.  No LDS.
// grid: (16 ctiles of 32 cols, 32 ksplits of 256 rows) = 512 blocks, 4 waves.
// Wave w: mt0 = w (rows 32w.., always valid), mt1 = 4+w (mt1=7 garbage,
// clamped loads, guarded epilogue).
// Frag conv (verified): reg r <-> k-rows kr+2r, kr+2r+1, kr = 16*step+8hi.
// C/D: col = lane&31, row = mt*32 + (r&3)+8*(r>>2)+4*hi.
// ---------------------------------------------------------------------------
#define UTX_LOADS(u0v, u1v, xv, step) {                                      \
    const int kr_ = r0 + 16*(step) + 8*hi;                                   \
    _Pragma("unroll") for (int j_ = 0; j_ < 8; ++j_) {                       \
        u0v[j_] = U[(kr_ + j_)*K_  + col0];                                  \
        u1v[j_] = U[(kr_ + j_)*K_  + col1];                                  \
        xv[j_]  = X[(kr_ + j_)*CIN_ + xcol];                                 \
    } }

#define UTX_CONSUME(u0v, u1v, xv) {                                          \
    union { uint u[4]; bf16x8 v; } a0_, a1_, b_;                             \
    _Pragma("unroll") for (int r_ = 0; r_ < 4; ++r_) {                       \
        a0_.u[r_] = packbf(u0v[2*r_], u0v[2*r_+1]);                          \
        a1_.u[r_] = packbf(u1v[2*r_], u1v[2*r_+1]);                          \
        b_.u[r_]  = packbf(xv[2*r_],  xv[2*r_+1]);                           \
    }                                                                        \
    acc0 = __builtin_amdgcn_mfma_f32_32x32x16_bf16(a0_.v, b_.v, acc0, 0,0,0);\
    acc1 = __builtin_amdgcn_mfma_f32_32x32x16_bf16(a1_.v, b_.v, acc1, 0,0,0); }

__global__ __launch_bounds__(256) void k_utx(
    const float* __restrict__ U, const float* __restrict__ X,
    float* __restrict__ T)
{
    const int c0  = blockIdx.x * 32;
    const int r0  = blockIdx.y * 256;
    const int tid = threadIdx.x;
    const int w   = tid >> 6;
    const int l   = tid & 63;
    const int lo  = l & 31;
    const int hi  = l >> 5;

    const int mt0  = w;
    const int mt1  = 4 + w;
    const int col0 = 32*mt0 + lo;
    const int col1 = min(32*mt1 + lo, K_ - 1);   // clamp: garbage discarded
    const int xcol = c0 + lo;

    f32x16 acc0 = {0}, acc1 = {0};

    float Au0[8], Au1[8], Ax[8], Bu0[8], Bu1[8], Bx[8];
    UTX_LOADS(Au0, Au1, Ax, 0);
    #pragma unroll
    for (int s = 0; s < 16; s += 2) {
        if (s + 1 < 16) UTX_LOADS(Bu0, Bu1, Bx, s + 1);
        UTX_CONSUME(Au0, Au1, Ax);
        if (s + 2 < 16) UTX_LOADS(Au0, Au1, Ax, s + 2);
        if (s + 1 < 16) UTX_CONSUME(Bu0, Bu1, Bx);
    }

    #pragma unroll
    for (int r = 0; r < 16; ++r) {
        const int rr  = (r & 3) + 8*(r >> 2) + 4*hi;
        const int mm0 = 32*mt0 + rr;             // < 128, always valid
        atomicAdd(&T[mm0*CIN_ + c0 + lo], acc0[r]);
        const int mm1 = 32*mt1 + rr;
        if (mm1 < K_)
            atomicAdd(&T[mm1*CIN_ + c0 + lo], acc1[r]);
    }
}

// ---------------------------------------------------------------------------
// G = T @ Ww   [200][256]; grid 50 blocks of 4 k-rows; thread = output col.
// ---------------------------------------------------------------------------
__global__ __launch_bounds__(256) void k_g(
    const float* __restrict__ T, const float* __restrict__ Ww,
    float* __restrict__ G)
{
    const int k0  = blockIdx.x * 4;
    const int c   = threadIdx.x;
    __shared__ float4 sT4[4][128];

    for (int j = threadIdx.x; j < 512; j += 256) {
        const int r = j >> 7, c4 = j & 127;
        sT4[r][c4] = reinterpret_cast<const float4*>(T)[(k0+r)*128 + c4];
    }
    __syncthreads();

    float a0 = 0.f, a1 = 0.f, a2 = 0.f, a3 = 0.f;
    for (int ci4 = 0; ci4 < 128; ++ci4) {
        const float w0 = Ww[(4*ci4+0)*HID_ + c];
        const float w1 = Ww[(4*ci4+1)*HID_ + c];
        const float w2 = Ww[(4*ci4+2)*HID_ + c];
        const float w3 = Ww[(4*ci4+3)*HID_ + c];
        float4 t;
        t = sT4[0][ci4]; a0 += t.x*w0 + t.y*w1 + t.z*w2 + t.w*w3;
        t = sT4[1][ci4]; a1 += t.x*w0 + t.y*w1 + t.z*w2 + t.w*w3;
        t = sT4[2][ci4]; a2 += t.x*w0 + t.y*w1 + t.z*w2 + t.w*w3;
        t = sT4[3][ci4]; a3 += t.x*w0 + t.y*w1 + t.z*w2 + t.w*w3;
    }
    G[(k0+0)*HID_ + c] = a0;
    G[(k0+1)*HID_ + c] = a1;
    G[(k0+2)*HID_ + c] = a2;
    G[(k0+3)*HID_ + c] = a3;
}

// ---------------------------------------------------------------------------
// hidden = (U*s) @ G + Wb   [8192][256]  via MFMA + fused BN batch stats.
// Epilogue: per-lane sum/sumsq of fragment cols, shfl fold, 4 atomics/lane.
// ---------------------------------------------------------------------------
__global__ __launch_bounds__(256) void k_hidden(
    const float* __restrict__ U, const float* __restrict__ s,
    const float* __restrict__ G, const float* __restrict__ Wb,
    float* __restrict__ hid, float* __restrict__ bnsum)
{
    const int c0  = blockIdx.x * 64;
    const int n0  = blockIdx.y * 128;
    const int tid = threadIdx.x;
    const int w   = tid >> 6;
    const int l   = tid & 63;
    const int lo  = l & 31;
    const int hi  = l >> 5;

    __shared__ uint  spkA[104][128];   // 53.2 KB
    __shared__ uint  spkB[104][64];    // 26.6 KB
    __shared__ float ss[K_];

    if (tid < K_) ss[tid] = s[tid];
    __syncthreads();

    for (int j = tid; j < 128*26; j += 256) {
        const int m = j & 127, g = j >> 7;
        uint4 pk = make_uint4(0u, 0u, 0u, 0u);
        if (g < 25) {
            const float4 a = *reinterpret_cast<const float4*>(&U[(n0+m)*K_ + 8*g]);
            const float4 b = *reinterpret_cast<const float4*>(&U[(n0+m)*K_ + 8*g + 4]);
            pk.x = packbf(a.x*ss[8*g+0], a.y*ss[8*g+1]);
            pk.y = packbf(a.z*ss[8*g+2], a.w*ss[8*g+3]);
            pk.z = packbf(b.x*ss[8*g+4], b.y*ss[8*g+5]);
            pk.w = packbf(b.z*ss[8*g+6], b.w*ss[8*g+7]);
        }
        spkA[4*g+0][m] = pk.x;
        spkA[4*g+1][m] = pk.y;
        spkA[4*g+2][m] = pk.z;
        spkA[4*g+3][m] = pk.w;
    }
    for (int j = tid; j < 64*26; j += 256) {
        const int c = j & 63, g = j >> 6;
        uint4 pk = make_uint4(0u, 0u, 0u, 0u);
        if (g < 25) {
            const float v0 = G[(8*g+0)*HID_ + c0+c], v1 = G[(8*g+1)*HID_ + c0+c];
            const float v2 = G[(8*g+2)*HID_ + c0+c], v3 = G[(8*g+3)*HID_ + c0+c];
            const float v4 = G[(8*g+4)*HID_ + c0+c], v5 = G[(8*g+5)*HID_ + c0+c];
            const float v6 = G[(8*g+6)*HID_ + c0+c], v7 = G[(8*g+7)*HID_ + c0+c];
            pk.x = packbf(v0, v1); pk.y = packbf(v2, v3);
            pk.z = packbf(v4, v5); pk.w = packbf(v6, v7);
        }
        spkB[4*g+0][c] = pk.x;
        spkB[4*g+1][c] = pk.y;
        spkB[4*g+2][c] = pk.z;
        spkB[4*g+3][c] = pk.w;
    }
    __syncthreads();

    f32x16 acc0 = {0}, acc1 = {0};
    #pragma unroll
    for (int t = 0; t < 13; ++t) {
        const int kp = 8*t + 4*hi;
        union { uint u[4]; bf16x8 v; } fa;
        fa.u[0] = spkA[kp+0][32*w + lo];
        fa.u[1] = spkA[kp+1][32*w + lo];
        fa.u[2] = spkA[kp+2][32*w + lo];
        fa.u[3] = spkA[kp+3][32*w + lo];
        UB b0, b1;
        b0.q.x = spkB[kp+0][lo];      b0.q.y = spkB[kp+1][lo];
        b0.q.z = spkB[kp+2][lo];      b0.q.w = spkB[kp+3][lo];
        b1.q.x = spkB[kp+0][32 + lo]; b1.q.y = spkB[kp+1][32 + lo];
        b1.q.z = spkB[kp+2][32 + lo]; b1.q.w = spkB[kp+3][32 + lo];
        acc0 = __builtin_amdgcn_mfma_f32_32x32x16_bf16(fa.v, b0.v, acc0, 0, 0, 0);
        acc1 = __builtin_amdgcn_mfma_f32_32x32x16_bf16(fa.v, b1.v, acc1, 0, 0, 0);
    }

    const float wb0 = Wb[c0 + lo], wb1 = Wb[c0 + 32 + lo];
    float sm0 = 0.f, sq0 = 0.f, sm1 = 0.f, sq1 = 0.f;
    #pragma unroll
    for (int r = 0; r < 16; ++r) {
        const int row = 32*w + (r & 3) + 8*(r >> 2) + 4*hi;
        const float h0 = acc0[r] + wb0;
        const float h1 = acc1[r] + wb1;
        hid[(n0+row)*HID_ + c0 + lo]      = h0;
        hid[(n0+row)*HID_ + c0 + 32 + lo] = h1;
        sm0 += h0; sq0 += h0*h0;
        sm1 += h1; sq1 += h1*h1;
    }
    // fold the two half-wave row groups (same column, rows differ by 4*hi)
    sm0 += __shfl_xor(sm0, 32); sq0 += __shfl_xor(sq0, 32);
    sm1 += __shfl_xor(sm1, 32); sq1 += __shfl_xor(sq1, 32);
    if (hi == 0) {
        atomicAdd(&bnsum[c0 + lo],              sm0);
        atomicAdd(&bnsum[HID_ + c0 + lo],       sq0);
        atomicAdd(&bnsum[c0 + 32 + lo],         sm1);
        atomicAdd(&bnsum[HID_ + c0 + 32 + lo],  sq1);
    }
}

// ---------------------------------------------------------------------------
// logits = relu(BN(hidden)) @ Mw + Mb; out = log_softmax.
// grid 256; block 256 = 32 rows x 8 col-slices of 32; LDS combine (pad 41).
// ---------------------------------------------------------------------------
__global__ __launch_bounds__(256) void k_logits(
    const float* __restrict__ hid, const float* __restrict__ bnsum,
    const float* __restrict__ gamma, const float* __restrict__ beta,
    const float* __restrict__ Mw, const float* __restrict__ Mb,
    float* __restrict__ outls)
{
    __shared__ float sc[HID_], sh[HID_], sMb[COUT_];
    __shared__ float sMw[HID_][COUT_];        // 40 KB
    __shared__ float sPart[8][32][41];        // 42 KB (pad 41: conflict-free)

    const int tid = threadIdx.x;
    const int r   = tid & 31;
    const int sl  = tid >> 5;

    {
        const float sm = bnsum[tid], sq = bnsum[HID_+tid];
        const float mu  = sm * (1.0f/N_);
        const float var = sq * (1.0f/N_) - mu*mu;
        const float a   = gamma[tid] * rsqrtf(var + EPS_);
        sc[tid] = a;
        sh[tid] = beta[tid] - mu*a;
    }
    for (int j = tid; j < HID_*COUT_/4; j += 256)
        reinterpret_cast<float4*>(&sMw[0][0])[j] = reinterpret_cast<const float4*>(Mw)[j];
    if (tid < COUT_) sMb[tid] = Mb[tid];
    __syncthreads();

    const int n  = blockIdx.x*32 + r;
    const int cb = sl * 32;
    float acc[COUT_];
    #pragma unroll
    for (int j = 0; j < COUT_; ++j) acc[j] = 0.f;

    const float4* hrow = reinterpret_cast<const float4*>(&hid[n*HID_ + cb]);
    #pragma unroll
    for (int c4 = 0; c4 < 8; ++c4) {
        const float4 h4 = hrow[c4];
        const float hv[4] = {h4.x, h4.y, h4.z, h4.w};
        #pragma unroll
        for (int q = 0; q < 4; ++q) {
            const int c = cb + 4*c4 + q;
            const float hn = fmaxf(hv[q]*sc[c] + sh[c], 0.f);
            #pragma unroll
            for (int j0 = 0; j0 < COUT_; j0 += 4) {
                const float4 wv = *reinterpret_cast<const float4*>(&sMw[c][j0]);
                acc[j0+0] += hn*wv.x; acc[j0+1] += hn*wv.y;
                acc[j0+2] += hn*wv.z; acc[j0+3] += hn*wv.w;
            }
        }
    }
    #pragma unroll
    for (int j = 0; j < COUT_; ++j) sPart[sl][r][j] = acc[j];
    __syncthreads();

    if (tid < 32) {
        const int n2 = blockIdx.x*32 + tid;
        float a2[COUT_];
        #pragma unroll
        for (int j = 0; j < COUT_; ++j) {
            float sum = sMb[j];
            #pragma unroll
            for (int s2 = 0; s2 < 8; ++s2) sum += sPart[s2][tid][j];
            a2[j] = sum;
        }
        float m = -1e30f;
        #pragma unroll
        for (int j = 0; j < COUT_; ++j) m = fmaxf(m, a2[j]);
        float ssum = 0.f;
        #pragma unroll
        for (int j = 0; j < COUT_; ++j) ssum += expf(a2[j] - m);
        const float lse = m + logf(ssum);
        #pragma unroll
        for (int j = 0; j < COUT_; ++j)
            outls[n2*COUT_ + j] = a2[j] - lse;
    }
}

// ---------------------------------------------------------------------------
extern "C" void kernel_launch(void* const* d_in, const int* in_sizes, int n_in,
                              void* d_out, int out_size, void* d_ws, size_t ws_size,
                              hipStream_t stream)
{
    const float* X        = (const float*)d_in[0];
    const float* La       = (const float*)d_in[1];
    const float* U        = (const float*)d_in[2];
    const float* eW1      = (const float*)d_in[3];
    const float* eb1      = (const float*)d_in[4];
    const float* eW2      = (const float*)d_in[5];
    const float* eb2      = (const float*)d_in[6];
    const float* eW3      = (const float*)d_in[7];
    const float* eb3      = (const float*)d_in[8];
    const float* gW1      = (const float*)d_in[9];
    const float* gb1      = (const float*)d_in[10];
    const float* gW2      = (const float*)d_in[11];
    const float* gb2      = (const float*)d_in[12];
    const float* Ww       = (const float*)d_in[13];
    const float* Wb       = (const float*)d_in[14];
    const float* bn_gamma = (const float*)d_in[15];
    const float* bn_beta  = (const float*)d_in[16];
    const float* Mw       = (const float*)d_in[17];
    const float* Mb       = (const float*)d_in[18];

    float* out   = (float*)d_out;
    float* ws    = (float*)d_ws;
    float* Vsum  = ws + WS_VSUM;
    float* bnsum = ws + WS_BNSUM;
    float* T     = ws + WS_T;
    float* s     = ws + WS_S;
    float* G     = ws + WS_G;

    float* outls = out;                 // [8192][40] log_softmax
    float* hid   = out + N_*COUT_;      // [8192][256] hidden (output 1)

    // zero Vsum + bnsum + T (k_utx / k_hidden accumulate with atomics)
    hipMemsetAsync(ws, 0, (size_t)(WS_T + K_*CIN_) * sizeof(float), stream);

    k_utx   <<<dim3(16, 32), 256, 0, stream>>>(U, X, T);
    k_expert<<<dim3(E_, 320), 256, 0, stream>>>(U, eW1, eb1, eW2, eb2, eW3, eb3, Vsum);
    k_gate  <<<1,   256, 0, stream>>>(La, gW1, gb1, gW2, gb2, Vsum, s);
    k_g     <<<50,  256, 0, stream>>>(T, Ww, G);
    k_hidden<<<dim3(4, 64), 256, 0, stream>>>(U, s, G, Wb, hid, bnsum);
    k_logits<<<256, 256, 0, stream>>>(hid, bnsum, bn_gamma, bn_beta, Mw, Mb, outls);
}